// Round 1
// baseline (966.265 us; speedup 1.0000x reference)
//
#include <hip/hip_runtime.h>
#include <math.h>

// ---------------------------------------------------------------------------
// SO3 convolution, fp32 end-to-end.
// Pipeline: k_setup(bins) -> k_fft_fwd -> k_beta_fwd -> k_so3mm -> k_inv
// Workspace: bin table (32KB slot) + Xf (33.5MB) + xh (5.6MB) + zh (11.2MB)
// ---------------------------------------------------------------------------

constexpr int NF   = 32;     // FFT size (2*B), same for input and output
constexpr int LTOT = 5456;
constexpr int Z    = 4;
constexpr int FI   = 32;
constexpr int FO   = 64;
constexpr int ZI   = Z * FI;   // 128
constexpr int ZO   = Z * FO;   // 256

__constant__ int d_LBASE[17] = {0,1,10,35,84,165,286,455,680,969,
                                1330,1771,2300,2925,3654,4495,5456};

// ---------------------------------------------------------------------------
// Setup: bin[t] = ((m mod 32) << 5) | (n mod 32) for t -> (l, m, n)
// ---------------------------------------------------------------------------
__global__ void k_setup(int* __restrict__ bin) {
    int t = blockIdx.x * 256 + threadIdx.x;
    if (t >= LTOT) return;
    int l = 0;
    while (t >= d_LBASE[l + 1]) l++;
    int r  = t - d_LBASE[l];
    int nl = 2 * l + 1;
    int mi = r / nl;
    int ni = r - mi * nl;
    int mm = (mi - l) & 31;
    int nn = (ni - l) & 31;
    bin[t] = (mm << 5) | nn;
}

// ---------------------------------------------------------------------------
// Forward FFT2 (e^{-i}) of one 32x32 plane per block.
// x: [z][i][b][a][g] real.   Xf: [zi][b][ma][ng] complex (float2).
// ---------------------------------------------------------------------------
__global__ __launch_bounds__(256) void k_fft_fwd(const float* __restrict__ x,
                                                 float2* __restrict__ Xf) {
    __shared__ float xs[1024];
    __shared__ float Gre[1056], Gim[1056];   // [a][ng] padded 33
    __shared__ float Wc[32], Ws[32];
    int tid = threadIdx.x;
    if (tid < 32) {
        float sv, cv;
        sincosf(6.28318530717958647692f * (float)tid / 32.0f, &sv, &cv);
        Wc[tid] = cv; Ws[tid] = sv;
    }
    const float* src = x + (size_t)blockIdx.x * 1024;
    for (int e = tid; e < 1024; e += 256) xs[e] = src[e];
    __syncthreads();
    // pass 1: over g (real input).  G[a][ng] = sum_g x[a][g] * e^{-2pi i ng g/32}
    for (int e = tid; e < 1024; e += 256) {
        int a = e >> 5, ng = e & 31;
        float re = 0.f, im = 0.f;
#pragma unroll
        for (int g = 0; g < 32; g++) {
            float v = xs[(a << 5) + g];
            int idx = (ng * g) & 31;
            re += v * Wc[idx];
            im -= v * Ws[idx];
        }
        Gre[a * 33 + ng] = re;
        Gim[a * 33 + ng] = im;
    }
    __syncthreads();
    // pass 2: over a.  Xf[ma][ng] = sum_a G[a][ng] * e^{-2pi i ma a/32}
    float2* dst = Xf + (size_t)blockIdx.x * 1024;
    for (int e = tid; e < 1024; e += 256) {
        int ma = e >> 5, ng = e & 31;
        float re = 0.f, im = 0.f;
#pragma unroll
        for (int a = 0; a < 32; a++) {
            float gr = Gre[a * 33 + ng], gi = Gim[a * 33 + ng];
            int idx = (ma * a) & 31;
            float c = Wc[idx], s = Ws[idx];
            re += gr * c + gi * s;
            im += gi * c - gr * s;
        }
        dst[e] = make_float2(re, im);
    }
}

// ---------------------------------------------------------------------------
// Beta contraction: xh[t][zi] = sum_b wf[b][t] * Xf[zi][b][bin[t]]
// grid: (zi=128) x (l=16)
// ---------------------------------------------------------------------------
__global__ __launch_bounds__(256) void k_beta_fwd(const float2* __restrict__ Xf,
                                                  const float* __restrict__ wf,
                                                  const int* __restrict__ bin,
                                                  float2* __restrict__ xh) {
    int l  = blockIdx.x & 15;
    int zi = blockIdx.x >> 4;
    int base = d_LBASE[l];
    int cnt  = d_LBASE[l + 1] - base;
    const float2* plane = Xf + (size_t)zi * 32 * 1024;
    for (int r = threadIdx.x; r < cnt; r += 256) {
        int t  = base + r;
        int bn = bin[t];
        float ax = 0.f, ay = 0.f;
#pragma unroll 4
        for (int b = 0; b < 32; b++) {
            float  w = wf[b * LTOT + t];
            float2 v = plane[b * 1024 + bn];
            ax += w * v.x;
            ay += w * v.y;
        }
        xh[(size_t)t * ZI + zi] = make_float2(ax, ay);
    }
}

// ---------------------------------------------------------------------------
// Per-l complex block GEMM, yh built on the fly from D x kernel.
// zh[base + m*nl + n][z*64+o] = sum_{k,i} xh[base+m*nl+k][z*32+i] * yh[base+k*nl+n][i*64+o]
// grid: 800 blocks = sum_l nl * ceil(nl/8); block = 128 threads (z, o/4, mi-half)
// ---------------------------------------------------------------------------
__global__ __launch_bounds__(128) void k_so3mm(const float2* __restrict__ xh,
                                               const float* __restrict__ Dre,
                                               const float* __restrict__ Dim,
                                               const float* __restrict__ ker,
                                               float2* __restrict__ zh) {
    __shared__ __align__(16) float2 As[1024];   // [ml][i][z] : ml*128 + i*4 + z
    __shared__ __align__(16) float2 Bs[2048];   // [i][o]     : i*64 + o

    // decode blockIdx -> (l, ni, mc)
    int rem = blockIdx.x;
    int l = 0, nl = 1, mcn = 1;
    for (l = 0; l < 16; l++) {
        nl  = 2 * l + 1;
        mcn = (nl + 7) >> 3;
        int c = nl * mcn;
        if (rem < c) break;
        rem -= c;
    }
    int ni     = rem / mcn;
    int mc     = rem - ni * mcn;
    int base   = d_LBASE[l];
    int mi0    = mc * 8;
    int mcount = min(8, nl - mi0);

    int tid = threadIdx.x;
    int z   = tid & 3;
    int og  = (tid >> 2) & 15;
    int ms  = tid >> 6;   // 0/1 -> ml = ms*4 + j

    float2 acc[4][4];
#pragma unroll
    for (int a = 0; a < 4; a++)
#pragma unroll
        for (int b2 = 0; b2 < 4; b2++) acc[a][b2] = make_float2(0.f, 0.f);

    for (int ki = 0; ki < nl; ki++) {
        // stage A (transposed to [ml][i][z] for conflict-light reads)
        for (int idx = tid; idx < 1024; idx += 128) {
            int ml = idx >> 7;
            int zi = idx & 127;
            int zz = zi >> 5, ii = zi & 31;
            float2 v = make_float2(0.f, 0.f);
            if (ml < mcount) {
                int row = base + (mi0 + ml) * nl + ki;
                v = xh[(size_t)row * ZI + zi];
            }
            As[ml * 128 + (ii << 2) + zz] = v;
        }
        // stage B: build yh row (k=ki, n=ni) from D * kernel
        int t2 = base + ki * nl + ni;
        float dre[12], dim_[12];
#pragma unroll
        for (int j = 0; j < 12; j++) {
            dre[j]  = Dre[t2 * 12 + j];
            dim_[j] = Dim[t2 * 12 + j];
        }
        for (int io = tid; io < 2048; io += 128) {
            const float4* kp = (const float4*)(ker + io * 12);
            float4 ka = kp[0], kb = kp[1], kc = kp[2];
            float kv[12] = {ka.x, ka.y, ka.z, ka.w,
                            kb.x, kb.y, kb.z, kb.w,
                            kc.x, kc.y, kc.z, kc.w};
            float sr = 0.f, si = 0.f;
#pragma unroll
            for (int j = 0; j < 12; j++) {
                sr += dre[j]  * kv[j];
                si += dim_[j] * kv[j];
            }
            Bs[io] = make_float2(sr, si);
        }
        __syncthreads();
        // MAC: 4 mi x 4 o per thread
#pragma unroll 4
        for (int i = 0; i < 32; i++) {
            const float4* b4 = (const float4*)(Bs + i * 64 + (og << 2));
            float4 b01 = b4[0];
            float4 b23 = b4[1];
#pragma unroll
            for (int j = 0; j < 4; j++) {
                float2 av = As[((ms << 2) + j) * 128 + (i << 2) + z];
                acc[j][0].x += av.x * b01.x - av.y * b01.y;
                acc[j][0].y += av.x * b01.y + av.y * b01.x;
                acc[j][1].x += av.x * b01.z - av.y * b01.w;
                acc[j][1].y += av.x * b01.w + av.y * b01.z;
                acc[j][2].x += av.x * b23.x - av.y * b23.y;
                acc[j][2].y += av.x * b23.y + av.y * b23.x;
                acc[j][3].x += av.x * b23.z - av.y * b23.w;
                acc[j][3].y += av.x * b23.w + av.y * b23.z;
            }
        }
        __syncthreads();
    }
    // epilogue
#pragma unroll
    for (int j = 0; j < 4; j++) {
        int ml = (ms << 2) + j;
        if (ml < mcount) {
            int row = base + (mi0 + ml) * nl + ni;
            float2* dst = zh + (size_t)row * ZO + (z << 6) + (og << 2);
            dst[0] = acc[j][0];
            dst[1] = acc[j][1];
            dst[2] = acc[j][2];
            dst[3] = acc[j][3];
        }
    }
}

// ---------------------------------------------------------------------------
// Inverse: per (zo, beta): accumulate frequency plane P from zh * wigner_inv
// (per-l chunks -> no bin collisions between barriers), then inverse DFT2
// (e^{+i}, x 1/1024) and write out[z][o][b][a][g] + bias[o].
// grid: (zo=256) x (beta-quarter=4); each block does 8 betas.
// ---------------------------------------------------------------------------
__global__ __launch_bounds__(256) void k_inv(const float2* __restrict__ zh,
                                             const float* __restrict__ wi,
                                             const int* __restrict__ bin,
                                             const float* __restrict__ bias,
                                             float* __restrict__ out) {
    __shared__ float2 zrow[LTOT];     // 43648 B
    __shared__ float2 P[1056];        // [ma][ng] padded 33
    __shared__ float2 T[1056];        // [ma][g]  padded 33
    __shared__ float Wc[32], Ws[32];

    int tid = threadIdx.x;
    int zo  = blockIdx.x >> 2;
    int bq  = blockIdx.x & 3;
    if (tid < 32) {
        float sv, cv;
        sincosf(6.28318530717958647692f * (float)tid / 32.0f, &sv, &cv);
        Wc[tid] = cv; Ws[tid] = sv;
    }
    for (int t = tid; t < LTOT; t += 256) zrow[t] = zh[(size_t)t * ZO + zo];
    float bv = bias[zo & 63];
    __syncthreads();

    for (int b = bq * 8; b < bq * 8 + 8; b++) {
        for (int e = tid; e < 1056; e += 256) P[e] = make_float2(0.f, 0.f);
        __syncthreads();
        for (int l = 0; l < 16; l++) {
            int base = d_LBASE[l];
            int cnt  = d_LBASE[l + 1] - base;
            for (int r = tid; r < cnt; r += 256) {
                int t  = base + r;
                float  w = wi[b * LTOT + t];
                float2 v = zrow[t];
                int bn  = bin[t];
                int idx = (bn >> 5) * 33 + (bn & 31);
                P[idx].x += w * v.x;
                P[idx].y += w * v.y;
            }
            __syncthreads();
        }
        // pass 1: T[ma][g] = sum_ng P[ma][ng] * e^{+2pi i ng g/32}
        for (int e = tid; e < 1024; e += 256) {
            int ma = e >> 5, g = e & 31;
            float re = 0.f, im = 0.f;
#pragma unroll
            for (int ng = 0; ng < 32; ng++) {
                float2 p = P[ma * 33 + ng];
                int idx = (ng * g) & 31;
                float c = Wc[idx], s = Ws[idx];
                re += p.x * c - p.y * s;
                im += p.x * s + p.y * c;
            }
            T[ma * 33 + g] = make_float2(re, im);
        }
        __syncthreads();
        // pass 2: out[a][g] = Re( sum_ma T[ma][g] * e^{+2pi i ma a/32} ) / 1024 + bias
        float* dst = out + (size_t)zo * 32768 + b * 1024;
        for (int e = tid; e < 1024; e += 256) {
            int a = e >> 5, g = e & 31;
            float av = 0.f;
#pragma unroll
            for (int ma = 0; ma < 32; ma++) {
                float2 tv = T[ma * 33 + g];
                int idx = (ma * a) & 31;
                av += tv.x * Wc[idx] - tv.y * Ws[idx];
            }
            dst[e] = av * (1.0f / 1024.0f) + bv;
        }
        __syncthreads();
    }
}

// ---------------------------------------------------------------------------
extern "C" void kernel_launch(void* const* d_in, const int* in_sizes, int n_in,
                              void* d_out, int out_size, void* d_ws, size_t ws_size,
                              hipStream_t stream) {
    const float* x    = (const float*)d_in[0];
    const float* ker  = (const float*)d_in[1];
    const float* bias = (const float*)d_in[2];
    const float* wf   = (const float*)d_in[3];
    const float* wi   = (const float*)d_in[4];
    const float* Dre  = (const float*)d_in[5];
    const float* Dim  = (const float*)d_in[6];
    float* out = (float*)d_out;

    char* ws = (char*)d_ws;
    int*    bin = (int*)ws;                                        // 21824 B (slot 32768)
    float2* Xf  = (float2*)(ws + 32768);                           // 33554432 B
    float2* xh  = (float2*)(ws + 32768 + 33554432);                // 5586944 B
    float2* zh  = (float2*)(ws + 32768 + 33554432 + 5586944);      // 11173888 B

    hipLaunchKernelGGL(k_setup,    dim3(22),   dim3(256), 0, stream, bin);
    hipLaunchKernelGGL(k_fft_fwd,  dim3(4096), dim3(256), 0, stream, x, Xf);
    hipLaunchKernelGGL(k_beta_fwd, dim3(2048), dim3(256), 0, stream, Xf, wf, bin, xh);
    hipLaunchKernelGGL(k_so3mm,    dim3(800),  dim3(128), 0, stream, xh, Dre, Dim, ker, zh);
    hipLaunchKernelGGL(k_inv,      dim3(1024), dim3(256), 0, stream, zh, wi, bin, bias, out);
}

// Round 2
// 873.790 us; speedup vs baseline: 1.1058x; 1.1058x over previous
//
#include <hip/hip_runtime.h>
#include <math.h>

// ---------------------------------------------------------------------------
// SO3 convolution, fp32 end-to-end.
// Pipeline: k_setup -> k_fft_fwd -> k_beta_fwd -> k_gemm -> k_reduce -> k_inv
// k_gemm: per (l, n, k-chunk) block, C[(m,z),(n,o)] complex GEMM, M-tile 128,
//         N=64, B row built on the fly from D*kernel (once globally per (k,n)).
// Workspace: bin | xh | zh | union(Xf, zh_part)   (~59 MB)
// ---------------------------------------------------------------------------

constexpr int LTOT = 5456;
constexpr int Z    = 4;
constexpr int FI   = 32;
constexpr int FO   = 64;
constexpr int ZI   = Z * FI;   // 128
constexpr int ZO   = Z * FO;   // 256

__constant__ int d_LBASE[17] = {0,1,10,35,84,165,286,455,680,969,
                                1330,1771,2300,2925,3654,4495,5456};

// ---------------------------------------------------------------------------
__global__ void k_setup(int* __restrict__ bin) {
    int t = blockIdx.x * 256 + threadIdx.x;
    if (t >= LTOT) return;
    int l = 0;
    while (t >= d_LBASE[l + 1]) l++;
    int r  = t - d_LBASE[l];
    int nl = 2 * l + 1;
    int mi = r / nl;
    int ni = r - mi * nl;
    int mm = (mi - l) & 31;
    int nn = (ni - l) & 31;
    bin[t] = (mm << 5) | nn;
}

// ---------------------------------------------------------------------------
// Forward FFT2 (e^{-i}) of one 32x32 plane per block.
// x: [z][i][b][a][g] real.   Xf: [zi*32+b][ma][ng] complex.
// ---------------------------------------------------------------------------
__global__ __launch_bounds__(256) void k_fft_fwd(const float* __restrict__ x,
                                                 float2* __restrict__ Xf) {
    __shared__ float xs[1024];
    __shared__ float Gre[1056], Gim[1056];   // [a][ng] padded 33
    __shared__ float Wc[32], Ws[32];
    int tid = threadIdx.x;
    if (tid < 32) {
        float sv, cv;
        sincosf(6.28318530717958647692f * (float)tid / 32.0f, &sv, &cv);
        Wc[tid] = cv; Ws[tid] = sv;
    }
    const float* src = x + (size_t)blockIdx.x * 1024;
    for (int e = tid; e < 1024; e += 256) xs[e] = src[e];
    __syncthreads();
    for (int e = tid; e < 1024; e += 256) {
        int a = e >> 5, ng = e & 31;
        float re = 0.f, im = 0.f;
#pragma unroll
        for (int g = 0; g < 32; g++) {
            float v = xs[(a << 5) + g];
            int idx = (ng * g) & 31;
            re += v * Wc[idx];
            im -= v * Ws[idx];
        }
        Gre[a * 33 + ng] = re;
        Gim[a * 33 + ng] = im;
    }
    __syncthreads();
    float2* dst = Xf + (size_t)blockIdx.x * 1024;
    for (int e = tid; e < 1024; e += 256) {
        int ma = e >> 5, ng = e & 31;
        float re = 0.f, im = 0.f;
#pragma unroll
        for (int a = 0; a < 32; a++) {
            float gr = Gre[a * 33 + ng], gi = Gim[a * 33 + ng];
            int idx = (ma * a) & 31;
            float c = Wc[idx], s = Ws[idx];
            re += gr * c + gi * s;
            im += gi * c - gr * s;
        }
        dst[e] = make_float2(re, im);
    }
}

// ---------------------------------------------------------------------------
// Beta contraction: xh[t][zi] = sum_b wf[b][t] * Xf[zi][b][bin[t]]
// ---------------------------------------------------------------------------
__global__ __launch_bounds__(256) void k_beta_fwd(const float2* __restrict__ Xf,
                                                  const float* __restrict__ wf,
                                                  const int* __restrict__ bin,
                                                  float2* __restrict__ xh) {
    int l  = blockIdx.x & 15;
    int zi = blockIdx.x >> 4;
    int base = d_LBASE[l];
    int cnt  = d_LBASE[l + 1] - base;
    const float2* plane = Xf + (size_t)zi * 32 * 1024;
    for (int r = threadIdx.x; r < cnt; r += 256) {
        int t  = base + r;
        int bn = bin[t];
        float ax = 0.f, ay = 0.f;
#pragma unroll 4
        for (int b = 0; b < 32; b++) {
            float  w = wf[b * LTOT + t];
            float2 v = plane[b * 1024 + bn];
            ax += w * v.x;
            ay += w * v.y;
        }
        xh[(size_t)t * ZI + zi] = make_float2(ax, ay);
    }
}

// ---------------------------------------------------------------------------
// Complex GEMM per (l, n, kchunk). Block: 256 threads.
// M-tile = 128 rows (mz = m*4+z, m<nl), N = 64 (o), K-chunk = up to 8 k x 32 i.
// As[i][mz] stride 132; Bs[i][o] built from D*kernel row t2 = base+k*nl+n.
// Output: zh_part[kc][base+m*nl+n][z*64+o]
// ---------------------------------------------------------------------------
__global__ __launch_bounds__(256) void k_gemm(const float2* __restrict__ xh,
                                              const float* __restrict__ Dre,
                                              const float* __restrict__ Dim,
                                              const float* __restrict__ ker,
                                              float2* __restrict__ zh_part) {
    __shared__ __align__(16) float2 As[32 * 132];   // 33792 B
    __shared__ __align__(16) float2 Bs[2048];       // 16384 B

    // decode blockIdx -> (l, n, kc); big l first
    int rem = blockIdx.x;
    int l = 15, nl = 31, kcn = 4;
    for (l = 15; l >= 0; l--) {
        nl  = 2 * l + 1;
        kcn = (nl + 7) >> 3;
        int c = nl * kcn;
        if (rem < c) break;
        rem -= c;
    }
    int n    = rem / kcn;
    int kc   = rem - n * kcn;
    int base = d_LBASE[l];
    int k0   = kc * 8;
    int k1   = min(k0 + 8, nl);

    int tid = threadIdx.x;
    int og  = tid & 15;          // o0 = og*4
    int o0  = og << 2;
    int mz0 = (tid >> 4) << 3;   // 8 consecutive mz per thread

    float2 acc[8][4];
#pragma unroll
    for (int j = 0; j < 8; j++)
#pragma unroll
        for (int q = 0; q < 4; q++) acc[j][q] = make_float2(0.f, 0.f);

    // zero-fill As once (padding rows mz >= 4*nl stay zero across k iterations)
    for (int e = tid; e < 32 * 132; e += 256) As[e] = make_float2(0.f, 0.f);
    __syncthreads();

    int alim = nl << 7;   // nl*128 staged A elements per k
    for (int k = k0; k < k1; ++k) {
        // stage A: xh rows (base + m*nl + k), 128 (z,i) each -> As[i][m*4+z]
        for (int e = tid; e < alim; e += 256) {
            int m  = e >> 7;
            int zi = e & 127;
            float2 v = xh[(size_t)(base + m * nl + k) * ZI + zi];
            As[(zi & 31) * 132 + (m << 2) + (zi >> 5)] = v;
        }
        // build B row t2 = (k,n): Bs[i*64+o] = sum_j D[t2][j]*ker[i][o][j]
        int t2 = base + k * nl + n;
        float dre[12], dim12[12];
#pragma unroll
        for (int j = 0; j < 12; j++) {
            dre[j]   = Dre[t2 * 12 + j];
            dim12[j] = Dim[t2 * 12 + j];
        }
        for (int io = tid; io < 2048; io += 256) {
            const float4* kp = (const float4*)(ker + io * 12);
            float4 ka = kp[0], kb = kp[1], kcv = kp[2];
            float kv[12] = {ka.x, ka.y, ka.z, ka.w,
                            kb.x, kb.y, kb.z, kb.w,
                            kcv.x, kcv.y, kcv.z, kcv.w};
            float sr = 0.f, si = 0.f;
#pragma unroll
            for (int j = 0; j < 12; j++) {
                sr += dre[j]   * kv[j];
                si += dim12[j] * kv[j];
            }
            Bs[io] = make_float2(sr, si);
        }
        __syncthreads();
        // inner MAC over i
#pragma unroll 4
        for (int i = 0; i < 32; i++) {
            const float4* bp = (const float4*)(Bs + i * 64 + o0);
            float4 B0 = bp[0], B1 = bp[1];
            const float4* ap = (const float4*)(As + i * 132 + mz0);
            float4 A0 = ap[0], A1 = ap[1], A2 = ap[2], A3 = ap[3];
            float ax[8] = {A0.x, A0.z, A1.x, A1.z, A2.x, A2.z, A3.x, A3.z};
            float ay[8] = {A0.y, A0.w, A1.y, A1.w, A2.y, A2.w, A3.y, A3.w};
            float bx[4] = {B0.x, B0.z, B1.x, B1.z};
            float by[4] = {B0.y, B0.w, B1.y, B1.w};
#pragma unroll
            for (int j = 0; j < 8; j++) {
#pragma unroll
                for (int q = 0; q < 4; q++) {
                    acc[j][q].x += ax[j] * bx[q] - ay[j] * by[q];
                    acc[j][q].y += ax[j] * by[q] + ay[j] * bx[q];
                }
            }
        }
        __syncthreads();
    }

    // epilogue: write valid rows
#pragma unroll
    for (int j = 0; j < 8; j++) {
        int mz = mz0 + j;
        int m  = mz >> 2;
        if (m < nl) {
            int z   = mz & 3;
            int row = base + m * nl + n;
            float2* dst = zh_part + ((size_t)kc * LTOT + row) * ZO + (z << 6) + o0;
            float4* d4 = (float4*)dst;
            d4[0] = make_float4(acc[j][0].x, acc[j][0].y, acc[j][1].x, acc[j][1].y);
            d4[1] = make_float4(acc[j][2].x, acc[j][2].y, acc[j][3].x, acc[j][3].y);
        }
    }
}

// ---------------------------------------------------------------------------
// Reduce K-partials: zh[t][zo] = sum_{kc < kcn(l(t))} zh_part[kc][t][zo]
// grid: LTOT blocks x 256 threads (one t per block).
// ---------------------------------------------------------------------------
__global__ __launch_bounds__(256) void k_reduce(const float2* __restrict__ zh_part,
                                                float2* __restrict__ zh) {
    int t = blockIdx.x;
    int l = 0;
    while (t >= d_LBASE[l + 1]) l++;
    int kcn = ((2 * l + 1) + 7) >> 3;
    int zo  = threadIdx.x;
    float2 s = zh_part[(size_t)t * ZO + zo];
    for (int kc = 1; kc < kcn; kc++) {
        float2 v = zh_part[((size_t)kc * LTOT + t) * ZO + zo];
        s.x += v.x; s.y += v.y;
    }
    zh[(size_t)t * ZO + zo] = s;
}

// ---------------------------------------------------------------------------
// Inverse transform.
// ---------------------------------------------------------------------------
__global__ __launch_bounds__(256) void k_inv(const float2* __restrict__ zh,
                                             const float* __restrict__ wi,
                                             const int* __restrict__ bin,
                                             const float* __restrict__ bias,
                                             float* __restrict__ out) {
    __shared__ float2 zrow[LTOT];
    __shared__ float2 P[1056];
    __shared__ float2 T[1056];
    __shared__ float Wc[32], Ws[32];

    int tid = threadIdx.x;
    int zo  = blockIdx.x >> 2;
    int bq  = blockIdx.x & 3;
    if (tid < 32) {
        float sv, cv;
        sincosf(6.28318530717958647692f * (float)tid / 32.0f, &sv, &cv);
        Wc[tid] = cv; Ws[tid] = sv;
    }
    for (int t = tid; t < LTOT; t += 256) zrow[t] = zh[(size_t)t * ZO + zo];
    float bv = bias[zo & 63];
    __syncthreads();

    for (int b = bq * 8; b < bq * 8 + 8; b++) {
        for (int e = tid; e < 1056; e += 256) P[e] = make_float2(0.f, 0.f);
        __syncthreads();
        for (int l = 0; l < 16; l++) {
            int base = d_LBASE[l];
            int cnt  = d_LBASE[l + 1] - base;
            for (int r = tid; r < cnt; r += 256) {
                int t  = base + r;
                float  w = wi[b * LTOT + t];
                float2 v = zrow[t];
                int bn  = bin[t];
                int idx = (bn >> 5) * 33 + (bn & 31);
                P[idx].x += w * v.x;
                P[idx].y += w * v.y;
            }
            __syncthreads();
        }
        for (int e = tid; e < 1024; e += 256) {
            int ma = e >> 5, g = e & 31;
            float re = 0.f, im = 0.f;
#pragma unroll
            for (int ng = 0; ng < 32; ng++) {
                float2 p = P[ma * 33 + ng];
                int idx = (ng * g) & 31;
                float c = Wc[idx], s = Ws[idx];
                re += p.x * c - p.y * s;
                im += p.x * s + p.y * c;
            }
            T[ma * 33 + g] = make_float2(re, im);
        }
        __syncthreads();
        float* dst = out + (size_t)zo * 32768 + b * 1024;
        for (int e = tid; e < 1024; e += 256) {
            int a = e >> 5, g = e & 31;
            float av = 0.f;
#pragma unroll
            for (int ma = 0; ma < 32; ma++) {
                float2 tv = T[ma * 33 + g];
                int idx = (ma * a) & 31;
                av += tv.x * Wc[idx] - tv.y * Ws[idx];
            }
            dst[e] = av * (1.0f / 1024.0f) + bv;
        }
        __syncthreads();
    }
}

// ---------------------------------------------------------------------------
extern "C" void kernel_launch(void* const* d_in, const int* in_sizes, int n_in,
                              void* d_out, int out_size, void* d_ws, size_t ws_size,
                              hipStream_t stream) {
    const float* x    = (const float*)d_in[0];
    const float* ker  = (const float*)d_in[1];
    const float* bias = (const float*)d_in[2];
    const float* wf   = (const float*)d_in[3];
    const float* wi   = (const float*)d_in[4];
    const float* Dre  = (const float*)d_in[5];
    const float* Dim  = (const float*)d_in[6];
    float* out = (float*)d_out;

    // layout: bin(32KB) | xh(5.59MB) | zh(11.17MB) | union(Xf 33.55MB, zh_part 44.70MB)
    char* ws = (char*)d_ws;
    int*    bin     = (int*)ws;
    float2* xh      = (float2*)(ws + 32768);
    float2* zh      = (float2*)(ws + 32768 + 5586944);
    char*   xu      = ws + 32768 + 5586944 + 11173888;
    float2* Xf      = (float2*)xu;
    float2* zh_part = (float2*)xu;   // reuses Xf region (Xf dead after k_beta_fwd)

    hipLaunchKernelGGL(k_setup,    dim3(22),   dim3(256), 0, stream, bin);
    hipLaunchKernelGGL(k_fft_fwd,  dim3(4096), dim3(256), 0, stream, x, Xf);
    hipLaunchKernelGGL(k_beta_fwd, dim3(2048), dim3(256), 0, stream, Xf, wf, bin, xh);
    hipLaunchKernelGGL(k_gemm,     dim3(800),  dim3(256), 0, stream, xh, Dre, Dim, ker, zh_part);
    hipLaunchKernelGGL(k_reduce,   dim3(LTOT), dim3(256), 0, stream, zh_part, zh);
    hipLaunchKernelGGL(k_inv,      dim3(1024), dim3(256), 0, stream, zh, wi, bin, bias, out);
}

// Round 3
// 603.052 us; speedup vs baseline: 1.6023x; 1.4489x over previous
//
#include <hip/hip_runtime.h>
#include <math.h>

// ---------------------------------------------------------------------------
// SO3 convolution. Transforms fp32; block GEMM via bf16 MFMA (complex-as-real).
// Pipeline: k_setup -> k_fft_fwd -> k_beta_fwd -> k_prep_A -> k_prep_B
//           -> k_gemm (MFMA) -> k_inv
// Per l: C[(m,z)][2(n*64+o)+c] = A[128 x 64nl] * B[64nl x 128nl],
//   A row 4m+z holds interleaved (re,im) of xh; B has [[br,bi],[-bi,br]] blocks.
// A and B LDS tiles are stored in MFMA fragment order (lane-linear).
// ---------------------------------------------------------------------------

typedef unsigned short u16;
typedef unsigned int   u32;
typedef __attribute__((ext_vector_type(8))) short  short8;   // 8 bf16
typedef __attribute__((ext_vector_type(4))) float  floatx4;

constexpr int LTOT = 5456;
constexpr int ZI   = 128;    // z*32+i
constexpr int ZO   = 256;    // z*64+o

__constant__ int d_LBASE[17] = {0,1,10,35,84,165,286,455,680,969,
                                1330,1771,2300,2925,3654,4495,5456};

__device__ inline u16 f2bf(float f) {
    u32 u = __float_as_uint(f);
    u += 0x7fff + ((u >> 16) & 1);
    return (u16)(u >> 16);
}

// ---------------------------------------------------------------------------
__global__ void k_setup(int* __restrict__ bin) {
    int t = blockIdx.x * 256 + threadIdx.x;
    if (t >= LTOT) return;
    int l = 0;
    while (t >= d_LBASE[l + 1]) l++;
    int r  = t - d_LBASE[l];
    int nl = 2 * l + 1;
    int mi = r / nl;
    int ni = r - mi * nl;
    bin[t] = (((mi - l) & 31) << 5) | ((ni - l) & 31);
}

// ---------------------------------------------------------------------------
// Forward FFT2 (e^{-i}) of one 32x32 plane per block.
// ---------------------------------------------------------------------------
__global__ __launch_bounds__(256) void k_fft_fwd(const float* __restrict__ x,
                                                 float2* __restrict__ Xf) {
    __shared__ float xs[1024];
    __shared__ float Gre[1056], Gim[1056];
    __shared__ float Wc[32], Ws[32];
    int tid = threadIdx.x;
    if (tid < 32) {
        float sv, cv;
        sincosf(6.28318530717958647692f * (float)tid / 32.0f, &sv, &cv);
        Wc[tid] = cv; Ws[tid] = sv;
    }
    const float* src = x + (size_t)blockIdx.x * 1024;
    for (int e = tid; e < 1024; e += 256) xs[e] = src[e];
    __syncthreads();
    for (int e = tid; e < 1024; e += 256) {
        int a = e >> 5, ng = e & 31;
        float re = 0.f, im = 0.f;
#pragma unroll
        for (int g = 0; g < 32; g++) {
            float v = xs[(a << 5) + g];
            int idx = (ng * g) & 31;
            re += v * Wc[idx];
            im -= v * Ws[idx];
        }
        Gre[a * 33 + ng] = re;
        Gim[a * 33 + ng] = im;
    }
    __syncthreads();
    float2* dst = Xf + (size_t)blockIdx.x * 1024;
    for (int e = tid; e < 1024; e += 256) {
        int ma = e >> 5, ng = e & 31;
        float re = 0.f, im = 0.f;
#pragma unroll
        for (int a = 0; a < 32; a++) {
            float gr = Gre[a * 33 + ng], gi = Gim[a * 33 + ng];
            int idx = (ma * a) & 31;
            float c = Wc[idx], s = Ws[idx];
            re += gr * c + gi * s;
            im += gi * c - gr * s;
        }
        dst[e] = make_float2(re, im);
    }
}

// ---------------------------------------------------------------------------
// Beta contraction: xh[t][zi] = sum_b wf[b][t] * Xf[zi][b][bin[t]]
// ---------------------------------------------------------------------------
__global__ __launch_bounds__(256) void k_beta_fwd(const float2* __restrict__ Xf,
                                                  const float* __restrict__ wf,
                                                  const int* __restrict__ bin,
                                                  float2* __restrict__ xh) {
    int l  = blockIdx.x & 15;
    int zi = blockIdx.x >> 4;
    int base = d_LBASE[l];
    int cnt  = d_LBASE[l + 1] - base;
    const float2* plane = Xf + (size_t)zi * 32 * 1024;
    for (int r = threadIdx.x; r < cnt; r += 256) {
        int t  = base + r;
        int bn = bin[t];
        float ax = 0.f, ay = 0.f;
#pragma unroll 4
        for (int b = 0; b < 32; b++) {
            float  w = wf[b * LTOT + t];
            float2 v = plane[b * 1024 + bn];
            ax += w * v.x;
            ay += w * v.y;
        }
        xh[(size_t)t * ZI + zi] = make_float2(ax, ay);
    }
}

// ---------------------------------------------------------------------------
// Build bf16 A in MFMA-fragment-tiled order.
// A_l (offset 8192*l^2 u16): tiles s in [0,2nl): flat = s*4096 + mtile*512 + L*8 + j
//   row = 4m+z (pad rows >=4nl left as ws poison: tiny bf16 values, rows unused)
//   kappa = 2*(k*32+i)+d ; s = 2k+(i>=16); kl = 2*(i&15)+d
//   L = (kl>>3)*16 + (row&15); j = kl&7
// ---------------------------------------------------------------------------
__global__ __launch_bounds__(128) void k_prep_A(const float2* __restrict__ xh,
                                                u16* __restrict__ Ab) {
    int t = blockIdx.x;
    int l = 0;
    while (t >= d_LBASE[l + 1]) l++;
    int nl = 2 * l + 1, base = d_LBASE[l];
    int r = t - base;
    int m = r / nl;
    int k = r - m * nl;
    int zi = threadIdx.x;
    int z = zi >> 5, i = zi & 31;
    float2 v = xh[(size_t)t * ZI + zi];
    u32 pack = (u32)f2bf(v.x) | ((u32)f2bf(v.y) << 16);
    int row = 4 * m + z;
    int s   = 2 * k + (i >> 4);
    int kl  = 2 * (i & 15);
    int L   = ((kl >> 3) << 4) + (row & 15);
    size_t off = (size_t)8192 * l * l + (size_t)s * 4096 + ((row >> 4) << 9) + (L << 3) + (kl & 7);
    *(u32*)(Ab + off) = pack;
}

// ---------------------------------------------------------------------------
// Build compact bf16 yh: yhb[t2][io] = pack(bf16(re), bf16(im)) of D*kernel.
// 8 t2-rows per block to amortize kernel reads.
// ---------------------------------------------------------------------------
__global__ __launch_bounds__(256) void k_prep_B(const float* __restrict__ Dre,
                                                const float* __restrict__ Dim,
                                                const float* __restrict__ ker,
                                                u32* __restrict__ yhb) {
    __shared__ float Ds[8][24];
    int t0  = blockIdx.x * 8;
    int tid = threadIdx.x;
    if (tid < 192) {
        int rr = tid / 24, jj = tid - rr * 24;
        Ds[rr][jj] = (jj < 12) ? Dre[(t0 + rr) * 12 + jj] : Dim[(t0 + rr) * 12 + jj - 12];
    }
    __syncthreads();
    for (int rep = 0; rep < 8; rep++) {
        int io = rep * 256 + tid;
        const float4* kp = (const float4*)(ker + io * 12);
        float4 ka = kp[0], kb = kp[1], kc = kp[2];
        float kv[12] = {ka.x, ka.y, ka.z, ka.w, kb.x, kb.y, kb.z, kb.w,
                        kc.x, kc.y, kc.z, kc.w};
#pragma unroll
        for (int rr = 0; rr < 8; rr++) {
            float sr = 0.f, si = 0.f;
#pragma unroll
            for (int j = 0; j < 12; j++) {
                sr += Ds[rr][j]      * kv[j];
                si += Ds[rr][12 + j] * kv[j];
            }
            yhb[(size_t)(t0 + rr) * 2048 + io] = (u32)f2bf(sr) | ((u32)f2bf(si) << 16);
        }
    }
}

// ---------------------------------------------------------------------------
// MFMA GEMM. 512 blocks = sum_l 2*(2l+1), big l first: block = (l, n, oh).
// Block: 256 thr, C tile 128 x 64 real cols, K-loop S = 2nl steps of 32.
// Wave w: rows [32w,32w+32) x all 64 cols: 2x4 mfma_f32_16x16x32_bf16 per step.
// ---------------------------------------------------------------------------
__global__ __launch_bounds__(256) void k_gemm(const u16* __restrict__ Ab,
                                              const u32* __restrict__ yhb,
                                              float* __restrict__ zh) {
    __shared__ __align__(16) u16 As[4096];   // 8 mtiles x 64 lanes x 8
    __shared__ __align__(16) u16 Bs[2048];   // 4 ntiles x 64 lanes x 8

    int rem = blockIdx.x, l, nl = 1;
    for (l = 15; l >= 0; l--) {
        nl = 2 * l + 1;
        int c = nl * 2;
        if (rem < c) break;
        rem -= c;
    }
    int n  = rem >> 1;
    int oh = rem & 1;
    int base = d_LBASE[l];
    const u16* Ag = Ab + (size_t)8192 * l * l;
    int S = 2 * nl;

    int tid = threadIdx.x, lane = tid & 63, w = tid >> 6;

    // B staging decode (thread owns 16B chunk tid of Bs)
    int kh = (tid >> 4) & 3;
    int nu = ((tid >> 6) << 4) + (tid & 15);   // local real col
    int oo = (oh << 5) + (nu >> 1);
    int cc = nu & 1;

    floatx4 acc[2][4];
#pragma unroll
    for (int a = 0; a < 2; a++)
#pragma unroll
        for (int b = 0; b < 4; b++) acc[a][b] = (floatx4)0.f;

    for (int s = 0; s < S; s++) {
        // A stage: 32B/thread, fully linear
        const uint4* ap = (const uint4*)(Ag + (size_t)s * 4096);
        uint4 a0 = ap[tid * 2], a1 = ap[tid * 2 + 1];
        // B stage: 4 complex yh values -> one 16B fragment chunk
        int k = s >> 1, ih = s & 1;
        const u32* yr = yhb + (size_t)(base + k * nl + n) * 2048
                        + (((ih << 4) + (kh << 2)) << 6) + oo;
        u32 b0 = yr[0], b1 = yr[64], b2 = yr[128], b3 = yr[192];
        u32 p0, p1, p2, p3;
        if (cc == 0) {
            p0 = (b0 & 0xffffu) | ((b0 >> 16) << 16 ^ 0x80000000u);
            p1 = (b1 & 0xffffu) | ((b1 >> 16) << 16 ^ 0x80000000u);
            p2 = (b2 & 0xffffu) | ((b2 >> 16) << 16 ^ 0x80000000u);
            p3 = (b3 & 0xffffu) | ((b3 >> 16) << 16 ^ 0x80000000u);
        } else {
            p0 = (b0 >> 16) | (b0 << 16);
            p1 = (b1 >> 16) | (b1 << 16);
            p2 = (b2 >> 16) | (b2 << 16);
            p3 = (b3 >> 16) | (b3 << 16);
        }
        {
            uint4* aq = (uint4*)&As[tid << 4];
            aq[0] = a0; aq[1] = a1;
            *(uint4*)&Bs[tid << 3] = make_uint4(p0, p1, p2, p3);
        }
        __syncthreads();
        short8 af0 = *(const short8*)&As[((w << 1) + 0) * 512 + (lane << 3)];
        short8 af1 = *(const short8*)&As[((w << 1) + 1) * 512 + (lane << 3)];
#pragma unroll
        for (int nt = 0; nt < 4; nt++) {
            short8 bf = *(const short8*)&Bs[nt * 512 + (lane << 3)];
            acc[0][nt] = __builtin_amdgcn_mfma_f32_16x16x32_bf16(af0, bf, acc[0][nt], 0, 0, 0);
            acc[1][nt] = __builtin_amdgcn_mfma_f32_16x16x32_bf16(af1, bf, acc[1][nt], 0, 0, 0);
        }
        __syncthreads();
    }

    // epilogue: C row = 32w + 16mt + 4*(lane>>4) + r ; col = 16nt + (lane&15)
    int q = lane >> 4, cn = lane & 15;
#pragma unroll
    for (int mt = 0; mt < 2; mt++) {
#pragma unroll
        for (int nt = 0; nt < 4; nt++) {
            int nu2 = (nt << 4) + cn;
            int o2  = (oh << 5) + (nu2 >> 1);
            int c2  = nu2 & 1;
#pragma unroll
            for (int r = 0; r < 4; r++) {
                int R = (w << 5) + (mt << 4) + (q << 2) + r;
                int m = R >> 2, z = R & 3;
                if (m < nl) {
                    zh[((size_t)(base + m * nl + n) * ZO + (z << 6) + o2) * 2 + c2] =
                        acc[mt][nt][r];
                }
            }
        }
    }
}

// ---------------------------------------------------------------------------
// Inverse transform (unchanged from R2).
// ---------------------------------------------------------------------------
__global__ __launch_bounds__(256) void k_inv(const float2* __restrict__ zh,
                                             const float* __restrict__ wi,
                                             const int* __restrict__ bin,
                                             const float* __restrict__ bias,
                                             float* __restrict__ out) {
    __shared__ float2 zrow[LTOT];
    __shared__ float2 P[1056];
    __shared__ float2 T[1056];
    __shared__ float Wc[32], Ws[32];

    int tid = threadIdx.x;
    int zo  = blockIdx.x >> 2;
    int bq  = blockIdx.x & 3;
    if (tid < 32) {
        float sv, cv;
        sincosf(6.28318530717958647692f * (float)tid / 32.0f, &sv, &cv);
        Wc[tid] = cv; Ws[tid] = sv;
    }
    for (int t = tid; t < LTOT; t += 256) zrow[t] = zh[(size_t)t * ZO + zo];
    float bv = bias[zo & 63];
    __syncthreads();

    for (int b = bq * 8; b < bq * 8 + 8; b++) {
        for (int e = tid; e < 1056; e += 256) P[e] = make_float2(0.f, 0.f);
        __syncthreads();
        for (int l = 0; l < 16; l++) {
            int base = d_LBASE[l];
            int cnt  = d_LBASE[l + 1] - base;
            for (int r = tid; r < cnt; r += 256) {
                int t  = base + r;
                float  w = wi[b * LTOT + t];
                float2 v = zrow[t];
                int bn  = bin[t];
                int idx = (bn >> 5) * 33 + (bn & 31);
                P[idx].x += w * v.x;
                P[idx].y += w * v.y;
            }
            __syncthreads();
        }
        for (int e = tid; e < 1024; e += 256) {
            int ma = e >> 5, g = e & 31;
            float re = 0.f, im = 0.f;
#pragma unroll
            for (int ng = 0; ng < 32; ng++) {
                float2 p = P[ma * 33 + ng];
                int idx = (ng * g) & 31;
                float c = Wc[idx], s = Ws[idx];
                re += p.x * c - p.y * s;
                im += p.x * s + p.y * c;
            }
            T[ma * 33 + g] = make_float2(re, im);
        }
        __syncthreads();
        float* dst = out + (size_t)zo * 32768 + b * 1024;
        for (int e = tid; e < 1024; e += 256) {
            int a = e >> 5, g = e & 31;
            float av = 0.f;
#pragma unroll
            for (int ma = 0; ma < 32; ma++) {
                float2 tv = T[ma * 33 + g];
                int idx = (ma * a) & 31;
                av += tv.x * Wc[idx] - tv.y * Ws[idx];
            }
            dst[e] = av * (1.0f / 1024.0f) + bv;
        }
        __syncthreads();
    }
}

// ---------------------------------------------------------------------------
extern "C" void kernel_launch(void* const* d_in, const int* in_sizes, int n_in,
                              void* d_out, int out_size, void* d_ws, size_t ws_size,
                              hipStream_t stream) {
    const float* x    = (const float*)d_in[0];
    const float* ker  = (const float*)d_in[1];
    const float* bias = (const float*)d_in[2];
    const float* wf   = (const float*)d_in[3];
    const float* wi   = (const float*)d_in[4];
    const float* Dre  = (const float*)d_in[5];
    const float* Dim  = (const float*)d_in[6];
    float* out = (float*)d_out;

    // layout: bin(32KB) | xh(5.59MB) | zh(11.17MB) | buf = union(Xf 33.6MB, Ab 4.2MB + yhb 44.7MB)
    char* ws = (char*)d_ws;
    int*    bin = (int*)ws;
    float2* xh  = (float2*)(ws + 32768);
    float2* zh  = (float2*)(ws + 32768 + 5586944);
    char*   buf = ws + 32768 + 5586944 + 11173888;
    float2* Xf  = (float2*)buf;
    u16*    Ab  = (u16*)buf;                    // overlaps Xf (dead after beta_fwd)
    u32*    yhb = (u32*)(buf + 4194304);

    hipLaunchKernelGGL(k_setup,    dim3(22),   dim3(256), 0, stream, bin);
    hipLaunchKernelGGL(k_fft_fwd,  dim3(4096), dim3(256), 0, stream, x, Xf);
    hipLaunchKernelGGL(k_beta_fwd, dim3(2048), dim3(256), 0, stream, Xf, wf, bin, xh);
    hipLaunchKernelGGL(k_prep_A,   dim3(LTOT), dim3(128), 0, stream, xh, Ab);
    hipLaunchKernelGGL(k_prep_B,   dim3(682),  dim3(256), 0, stream, Dre, Dim, ker, yhb);
    hipLaunchKernelGGL(k_gemm,     dim3(512),  dim3(256), 0, stream, Ab, yhb, (float*)zh);
    hipLaunchKernelGGL(k_inv,      dim3(1024), dim3(256), 0, stream, zh, wi, bin, bias, out);
}

// Round 4
// 408.688 us; speedup vs baseline: 2.3643x; 1.4756x over previous
//
#include <hip/hip_runtime.h>
#include <math.h>

// ---------------------------------------------------------------------------
// SO3 convolution. Transforms fp32; block GEMM via bf16 MFMA (complex-as-real).
// Pipeline: k_fft_fwd -> k_beta_A (beta contraction fused w/ bf16 A-fragment
//           pack) -> k_prep_B -> k_gemm (MFMA) -> k_inv2 (gather + radix-2 IDFT)
// zh stored transposed [zo][t] so k_inv2 gathers coalesced rows.
// Workspace: union(Xf, yhb) | Ab | zh_T   (~60 MB)
// ---------------------------------------------------------------------------

typedef unsigned short u16;
typedef unsigned int   u32;
typedef __attribute__((ext_vector_type(8))) short  short8;   // 8 bf16
typedef __attribute__((ext_vector_type(4))) float  floatx4;

constexpr int LTOT = 5456;
constexpr int ZO   = 256;    // z*64+o

// l(2l-1)(2l+1)/3 prefix offsets; constexpr -> folds to immediates in unrolled code
constexpr int LB[17] = {0,1,10,35,84,165,286,455,680,969,
                        1330,1771,2300,2925,3654,4495,5456};

__device__ inline u16 f2bf(float f) {
    u32 u = __float_as_uint(f);
    u += 0x7fff + ((u >> 16) & 1);
    return (u16)(u >> 16);
}

// ---------------------------------------------------------------------------
// Forward FFT2 (e^{-i}) of one 32x32 plane per block. x: [z][i][b][a][g].
// Xf: [zi*32+b][ma][ng] complex.
// ---------------------------------------------------------------------------
__global__ __launch_bounds__(256) void k_fft_fwd(const float* __restrict__ x,
                                                 float2* __restrict__ Xf) {
    __shared__ float xs[1024];
    __shared__ float Gre[1056], Gim[1056];
    __shared__ float Wc[32], Ws[32];
    int tid = threadIdx.x;
    if (tid < 32) {
        float sv, cv;
        sincosf(6.28318530717958647692f * (float)tid / 32.0f, &sv, &cv);
        Wc[tid] = cv; Ws[tid] = sv;
    }
    const float* src = x + (size_t)blockIdx.x * 1024;
    for (int e = tid; e < 1024; e += 256) xs[e] = src[e];
    __syncthreads();
    for (int e = tid; e < 1024; e += 256) {
        int a = e >> 5, ng = e & 31;
        float re = 0.f, im = 0.f;
#pragma unroll
        for (int g = 0; g < 32; g++) {
            float v = xs[(a << 5) + g];
            int idx = (ng * g) & 31;
            re += v * Wc[idx];
            im -= v * Ws[idx];
        }
        Gre[a * 33 + ng] = re;
        Gim[a * 33 + ng] = im;
    }
    __syncthreads();
    float2* dst = Xf + (size_t)blockIdx.x * 1024;
    for (int e = tid; e < 1024; e += 256) {
        int ma = e >> 5, ng = e & 31;
        float re = 0.f, im = 0.f;
#pragma unroll
        for (int a = 0; a < 32; a++) {
            float gr = Gre[a * 33 + ng], gi = Gim[a * 33 + ng];
            int idx = (ma * a) & 31;
            float c = Wc[idx], s = Ws[idx];
            re += gr * c + gi * s;
            im += gi * c - gr * s;
        }
        dst[e] = make_float2(re, im);
    }
}

// ---------------------------------------------------------------------------
// Fused beta-contraction + bf16 A-fragment pack.
// Per bin (ma,ng): all l >= l0 share Xf[zi][b][ma*32+ng] -> Xf read exactly once.
// Grid: (ma 32) x (zig 16) = 512 blocks; thread = (zi_local 8, ng 32).
// acc[l] = sum_b wf[b][t(l)] * Xf[zi][b][bin];  pack -> Ab fragment layout.
// ---------------------------------------------------------------------------
__global__ __launch_bounds__(256) void k_beta_A(const float2* __restrict__ Xf,
                                                const float* __restrict__ wf,
                                                u16* __restrict__ Ab) {
    int ma  = blockIdx.x >> 4;
    int zig = blockIdx.x & 15;
    int tid = threadIdx.x;
    int zil = tid >> 5;
    int ng  = tid & 31;
    int zi  = zig * 8 + zil;
    int z = zi >> 5, i = zi & 31;
    int mh = (ma <= 15) ? ma : ma - 32;
    int nh = (ng <= 15) ? ng : ng - 32;
    int am = mh < 0 ? -mh : mh;
    int an = nh < 0 ? -nh : nh;
    int l0 = am > an ? am : an;    // 16 possible (ma==16) -> all l skipped

    int tl[16];
#pragma unroll
    for (int l = 0; l < 16; l++)
        tl[l] = LB[l] + (mh + l) * (2 * l + 1) + (nh + l);

    float2 acc[16];
#pragma unroll
    for (int l = 0; l < 16; l++) acc[l] = make_float2(0.f, 0.f);

    const float2* xp = Xf + (size_t)zi * 32 * 1024 + (ma << 5) + ng;
    for (int b = 0; b < 32; b++) {
        float2 v = xp[(size_t)b * 1024];
        const float* wfb = wf + b * LTOT;
#pragma unroll
        for (int l = 0; l < 16; l++) {
            if (l >= l0) {
                float w = wfb[tl[l]];
                acc[l].x += w * v.x;
                acc[l].y += w * v.y;
            }
        }
    }
    int s_i  = i >> 4;
    int kl   = 2 * (i & 15);
    int joff = kl & 7;
    int Lhi  = (kl >> 3) << 4;
#pragma unroll
    for (int l = 0; l < 16; l++) {
        if (l >= l0) {
            int mi = mh + l, ni = nh + l;
            int s   = 2 * ni + s_i;
            int row = 4 * mi + z;
            u32 pack = (u32)f2bf(acc[l].x) | ((u32)f2bf(acc[l].y) << 16);
            size_t off = (size_t)8192 * l * l + (size_t)s * 4096
                       + ((row >> 4) << 9) + ((Lhi + (row & 15)) << 3) + joff;
            *(u32*)(Ab + off) = pack;
        }
    }
}

// ---------------------------------------------------------------------------
// Build compact bf16 yh: yhb[t2][io] = pack(bf16(re), bf16(im)) of D*kernel.
// ---------------------------------------------------------------------------
__global__ __launch_bounds__(256) void k_prep_B(const float* __restrict__ Dre,
                                                const float* __restrict__ Dim,
                                                const float* __restrict__ ker,
                                                u32* __restrict__ yhb) {
    __shared__ float Ds[8][24];
    int t0  = blockIdx.x * 8;
    int tid = threadIdx.x;
    if (tid < 192) {
        int rr = tid / 24, jj = tid - rr * 24;
        Ds[rr][jj] = (jj < 12) ? Dre[(t0 + rr) * 12 + jj] : Dim[(t0 + rr) * 12 + jj - 12];
    }
    __syncthreads();
    for (int rep = 0; rep < 8; rep++) {
        int io = rep * 256 + tid;
        const float4* kp = (const float4*)(ker + io * 12);
        float4 ka = kp[0], kb = kp[1], kc = kp[2];
        float kv[12] = {ka.x, ka.y, ka.z, ka.w, kb.x, kb.y, kb.z, kb.w,
                        kc.x, kc.y, kc.z, kc.w};
#pragma unroll
        for (int rr = 0; rr < 8; rr++) {
            float sr = 0.f, si = 0.f;
#pragma unroll
            for (int j = 0; j < 12; j++) {
                sr += Ds[rr][j]      * kv[j];
                si += Ds[rr][12 + j] * kv[j];
            }
            yhb[(size_t)(t0 + rr) * 2048 + io] = (u32)f2bf(sr) | ((u32)f2bf(si) << 16);
        }
    }
}

// ---------------------------------------------------------------------------
// MFMA GEMM. 512 blocks = sum_l 2*(2l+1), big l first: block = (l, n, oh).
// Output transposed: zh_T[zo][t] (float pairs) for k_inv2's coalesced gather.
// ---------------------------------------------------------------------------
__global__ __launch_bounds__(256) void k_gemm(const u16* __restrict__ Ab,
                                              const u32* __restrict__ yhb,
                                              float* __restrict__ zhT) {
    __shared__ __align__(16) u16 As[4096];
    __shared__ __align__(16) u16 Bs[2048];

    int rem = blockIdx.x, l, nl = 1;
    for (l = 15; l >= 0; l--) {
        nl = 2 * l + 1;
        int c = nl * 2;
        if (rem < c) break;
        rem -= c;
    }
    int n  = rem >> 1;
    int oh = rem & 1;
    int base = LB[l];
    const u16* Ag = Ab + (size_t)8192 * l * l;
    int S = 2 * nl;

    int tid = threadIdx.x, lane = tid & 63, w = tid >> 6;

    int kh = (tid >> 4) & 3;
    int nu = ((tid >> 6) << 4) + (tid & 15);
    int oo = (oh << 5) + (nu >> 1);
    int cc = nu & 1;

    floatx4 acc[2][4];
#pragma unroll
    for (int a = 0; a < 2; a++)
#pragma unroll
        for (int b = 0; b < 4; b++) acc[a][b] = (floatx4)0.f;

    for (int s = 0; s < S; s++) {
        const uint4* ap = (const uint4*)(Ag + (size_t)s * 4096);
        uint4 a0 = ap[tid * 2], a1 = ap[tid * 2 + 1];
        int k = s >> 1, ih = s & 1;
        const u32* yr = yhb + (size_t)(base + k * nl + n) * 2048
                        + (((ih << 4) + (kh << 2)) << 6) + oo;
        u32 b0 = yr[0], b1 = yr[64], b2 = yr[128], b3 = yr[192];
        u32 p0, p1, p2, p3;
        if (cc == 0) {
            p0 = (b0 & 0xffffu) | ((b0 >> 16) << 16 ^ 0x80000000u);
            p1 = (b1 & 0xffffu) | ((b1 >> 16) << 16 ^ 0x80000000u);
            p2 = (b2 & 0xffffu) | ((b2 >> 16) << 16 ^ 0x80000000u);
            p3 = (b3 & 0xffffu) | ((b3 >> 16) << 16 ^ 0x80000000u);
        } else {
            p0 = (b0 >> 16) | (b0 << 16);
            p1 = (b1 >> 16) | (b1 << 16);
            p2 = (b2 >> 16) | (b2 << 16);
            p3 = (b3 >> 16) | (b3 << 16);
        }
        {
            uint4* aq = (uint4*)&As[tid << 4];
            aq[0] = a0; aq[1] = a1;
            *(uint4*)&Bs[tid << 3] = make_uint4(p0, p1, p2, p3);
        }
        __syncthreads();
        short8 af0 = *(const short8*)&As[((w << 1) + 0) * 512 + (lane << 3)];
        short8 af1 = *(const short8*)&As[((w << 1) + 1) * 512 + (lane << 3)];
#pragma unroll
        for (int nt = 0; nt < 4; nt++) {
            short8 bf = *(const short8*)&Bs[nt * 512 + (lane << 3)];
            acc[0][nt] = __builtin_amdgcn_mfma_f32_16x16x32_bf16(af0, bf, acc[0][nt], 0, 0, 0);
            acc[1][nt] = __builtin_amdgcn_mfma_f32_16x16x32_bf16(af1, bf, acc[1][nt], 0, 0, 0);
        }
        __syncthreads();
    }

    int q = lane >> 4, cn = lane & 15;
#pragma unroll
    for (int mt = 0; mt < 2; mt++) {
#pragma unroll
        for (int nt = 0; nt < 4; nt++) {
            int nu2 = (nt << 4) + cn;
            int o2  = (oh << 5) + (nu2 >> 1);
            int c2  = nu2 & 1;
#pragma unroll
            for (int r = 0; r < 4; r++) {
                int R = (w << 5) + (mt << 4) + (q << 2) + r;
                int m = R >> 2, z = R & 3;
                if (m < nl) {
                    int t  = base + m * nl + n;
                    int zo = (z << 6) + o2;
                    zhT[((size_t)zo * LTOT + t) * 2 + c2] = acc[mt][nt][r];
                }
            }
        }
    }
}

// ---------------------------------------------------------------------------
// Inverse: block = (zo, beta-pair). Gather P bins directly from zh_T (no
// scatter, no per-l barriers), then in-place radix-2 IDFT2 (rows in regs),
// stage output plane in LDS, coalesced write + bias.
// Grid: 4096 = (zo 256) x (bp 16); 256 threads; LDS ~17.5 KB.
// ---------------------------------------------------------------------------
__global__ __launch_bounds__(256) void k_inv2(const float2* __restrict__ zhT,
                                              const float* __restrict__ wi,
                                              const float* __restrict__ bias,
                                              float* __restrict__ out) {
    __shared__ float2 P[2][32 * 34];   // row stride 34 (16B-aligned rows)
    __shared__ float Wc[32], Ws[32];
    int tid = threadIdx.x;
    int zo = blockIdx.x >> 4;
    int bp = blockIdx.x & 15;
    int b0 = bp * 2;
    if (tid < 32) {
        float sv, cv;
        sincosf(6.28318530717958647692f * (float)tid / 32.0f, &sv, &cv);
        Wc[tid] = cv; Ws[tid] = sv;
    }
    // ---- gather phase: 4 bins per thread
    {
        int ng = tid & 31, mq = tid >> 5;
        int nh = (ng <= 15) ? ng : ng - 32;
        int an = nh < 0 ? -nh : nh;
        const float2* zr = zhT + (size_t)zo * LTOT;
        const float*  w0p = wi + (size_t)b0 * LTOT;
        const float*  w1p = w0p + LTOT;
#pragma unroll
        for (int j = 0; j < 4; j++) {
            int ma = mq + 8 * j;
            int mh = (ma <= 15) ? ma : ma - 32;
            int am = mh < 0 ? -mh : mh;
            int l0 = am > an ? am : an;
            float2 a0 = make_float2(0.f, 0.f), a1 = make_float2(0.f, 0.f);
#pragma unroll
            for (int l = 0; l < 16; l++) {
                if (l >= l0) {
                    int t = LB[l] + (mh + l) * (2 * l + 1) + (nh + l);
                    float2 zv = zr[t];
                    float w0 = w0p[t];
                    float w1 = w1p[t];
                    a0.x += w0 * zv.x; a0.y += w0 * zv.y;
                    a1.x += w1 * zv.x; a1.y += w1 * zv.y;
                }
            }
            P[0][ma * 34 + ng] = a0;
            P[1][ma * 34 + ng] = a1;
        }
    }
    __syncthreads();
    // ---- pass 1 (ng -> g), e^{+i}, radix-2, in-place per row
    {
        int p = tid >> 7, rr = tid & 127;
        int ma = rr >> 2, q = rr & 3;
        float2* prow = &P[p][ma * 34];
        float2 row[32];
#pragma unroll
        for (int ngi = 0; ngi < 32; ngi++) row[ngi] = prow[ngi];
        float2 Tv[8];
#pragma unroll
        for (int jj = 0; jj < 4; jj++) {
            int k = q * 4 + jj;
            float2 E = make_float2(0.f, 0.f), O = make_float2(0.f, 0.f);
#pragma unroll
            for (int h = 0; h < 16; h++) {
                int idx = (2 * h * k) & 31;
                float c = Wc[idx], s = Ws[idx];
                float2 e = row[2 * h], o = row[2 * h + 1];
                E.x += e.x * c - e.y * s;  E.y += e.x * s + e.y * c;
                O.x += o.x * c - o.y * s;  O.y += o.x * s + o.y * c;
            }
            float c = Wc[k], s = Ws[k];
            float2 wO = make_float2(O.x * c - O.y * s, O.x * s + O.y * c);
            Tv[jj]     = make_float2(E.x + wO.x, E.y + wO.y);
            Tv[4 + jj] = make_float2(E.x - wO.x, E.y - wO.y);
        }
        // same-wave row ownership: all row loads precede these stores
#pragma unroll
        for (int jj = 0; jj < 4; jj++) {
            prow[q * 4 + jj]      = Tv[jj];
            prow[q * 4 + jj + 16] = Tv[4 + jj];
        }
    }
    __syncthreads();
    // ---- pass 2 (ma -> a), real output, radix-2
    float vals[8];
    int p = tid >> 7, rr = tid & 127;
    int g = rr >> 2, q = rr & 3;
    {
        float2 col[32];
#pragma unroll
        for (int ma = 0; ma < 32; ma++) col[ma] = P[p][ma * 34 + g];
#pragma unroll
        for (int jj = 0; jj < 4; jj++) {
            int a = q * 4 + jj;
            float Ex = 0.f;
            float2 O = make_float2(0.f, 0.f);
#pragma unroll
            for (int h = 0; h < 16; h++) {
                int idx = (2 * h * a) & 31;
                float c = Wc[idx], s = Ws[idx];
                float2 e = col[2 * h], o = col[2 * h + 1];
                Ex  += e.x * c - e.y * s;
                O.x += o.x * c - o.y * s;
                O.y += o.x * s + o.y * c;
            }
            float wOx = O.x * Wc[a] - O.y * Ws[a];
            vals[jj]     = Ex + wOx;
            vals[4 + jj] = Ex - wOx;
        }
    }
    __syncthreads();
    float bv = bias[zo & 63];
    float* outS = (float*)&P[0][0];   // 8 KB staging fits in P[0]
#pragma unroll
    for (int jj = 0; jj < 4; jj++) {
        int a = q * 4 + jj;
        outS[p * 1024 + a * 32 + g]        = vals[jj]     * (1.f / 1024.f) + bv;
        outS[p * 1024 + (a + 16) * 32 + g] = vals[4 + jj] * (1.f / 1024.f) + bv;
    }
    __syncthreads();
    {
        int p2 = tid >> 7, r2 = tid & 127;
        const float4* sp = (const float4*)(outS + p2 * 1024);
        float4* dp = (float4*)(out + (size_t)zo * 32768 + (size_t)(b0 + p2) * 1024);
        dp[r2 * 2]     = sp[r2 * 2];
        dp[r2 * 2 + 1] = sp[r2 * 2 + 1];
    }
}

// ---------------------------------------------------------------------------
extern "C" void kernel_launch(void* const* d_in, const int* in_sizes, int n_in,
                              void* d_out, int out_size, void* d_ws, size_t ws_size,
                              hipStream_t stream) {
    const float* x    = (const float*)d_in[0];
    const float* ker  = (const float*)d_in[1];
    const float* bias = (const float*)d_in[2];
    const float* wf   = (const float*)d_in[3];
    const float* wi   = (const float*)d_in[4];
    const float* Dre  = (const float*)d_in[5];
    const float* Dim  = (const float*)d_in[6];
    float* out = (float*)d_out;

    // layout: buf0 = union(Xf 33.6MB, yhb 44.7MB) | Ab 4.2MB | zh_T 11.2MB
    // (yhb may overwrite Xf: k_prep_B launches after k_beta_A on the stream)
    char* ws = (char*)d_ws;
    float2* Xf  = (float2*)ws;
    u32*    yhb = (u32*)ws;
    u16*    Ab  = (u16*)(ws + 44695552);
    float*  zhT = (float*)(ws + 44695552 + 4194304);

    hipLaunchKernelGGL(k_fft_fwd, dim3(4096), dim3(256), 0, stream, x, Xf);
    hipLaunchKernelGGL(k_beta_A,  dim3(512),  dim3(256), 0, stream, Xf, wf, Ab);
    hipLaunchKernelGGL(k_prep_B,  dim3(682),  dim3(256), 0, stream, Dre, Dim, ker, yhb);
    hipLaunchKernelGGL(k_gemm,    dim3(512),  dim3(256), 0, stream, Ab, yhb, zhT);
    hipLaunchKernelGGL(k_inv2,    dim3(4096), dim3(256), 0, stream, (const float2*)zhT, wi, bias, out);
}

// Round 5
// 361.654 us; speedup vs baseline: 2.6718x; 1.1301x over previous
//
#include <hip/hip_runtime.h>
#include <math.h>

// ---------------------------------------------------------------------------
// SO3 convolution. Transforms fp32; block GEMM via bf16 MFMA (complex-as-real).
// Pipeline: k_fft_fwd -> k_beta_A (beta contraction fused w/ bf16 A-fragment
//           pack) -> k_prep_B -> k_gemm (MFMA) -> k_inv2 (gather + radix-2 IDFT)
// zh stored transposed [zo][t] so k_inv2 gathers coalesced rows.
// Workspace: union(Xf, yhb) | Ab | zh_T   (~60 MB)
// ---------------------------------------------------------------------------

typedef unsigned short u16;
typedef unsigned int   u32;
typedef __attribute__((ext_vector_type(8))) short  short8;   // 8 bf16
typedef __attribute__((ext_vector_type(4))) float  floatx4;

constexpr int LTOT = 5456;
constexpr int ZO   = 256;    // z*64+o

constexpr int LB[17] = {0,1,10,35,84,165,286,455,680,969,
                        1330,1771,2300,2925,3654,4495,5456};

__device__ inline u16 f2bf(float f) {
    u32 u = __float_as_uint(f);
    u += 0x7fff + ((u >> 16) & 1);
    return (u16)(u >> 16);
}

// ---------------------------------------------------------------------------
// Forward FFT2 (e^{-i}) of one 32x32 plane per block. x: [z][i][b][a][g].
// Xf: [zi*32+b][ma][ng] complex.
// ---------------------------------------------------------------------------
__global__ __launch_bounds__(256) void k_fft_fwd(const float* __restrict__ x,
                                                 float2* __restrict__ Xf) {
    __shared__ float xs[1024];
    __shared__ float Gre[1056], Gim[1056];
    __shared__ float Wc[32], Ws[32];
    int tid = threadIdx.x;
    if (tid < 32) {
        float sv, cv;
        sincosf(6.28318530717958647692f * (float)tid / 32.0f, &sv, &cv);
        Wc[tid] = cv; Ws[tid] = sv;
    }
    const float* src = x + (size_t)blockIdx.x * 1024;
    for (int e = tid; e < 1024; e += 256) xs[e] = src[e];
    __syncthreads();
    for (int e = tid; e < 1024; e += 256) {
        int a = e >> 5, ng = e & 31;
        float re = 0.f, im = 0.f;
#pragma unroll
        for (int g = 0; g < 32; g++) {
            float v = xs[(a << 5) + g];
            int idx = (ng * g) & 31;
            re += v * Wc[idx];
            im -= v * Ws[idx];
        }
        Gre[a * 33 + ng] = re;
        Gim[a * 33 + ng] = im;
    }
    __syncthreads();
    float2* dst = Xf + (size_t)blockIdx.x * 1024;
    for (int e = tid; e < 1024; e += 256) {
        int ma = e >> 5, ng = e & 31;
        float re = 0.f, im = 0.f;
#pragma unroll
        for (int a = 0; a < 32; a++) {
            float gr = Gre[a * 33 + ng], gi = Gim[a * 33 + ng];
            int idx = (ma * a) & 31;
            float c = Wc[idx], s = Ws[idx];
            re += gr * c + gi * s;
            im += gi * c - gr * s;
        }
        dst[e] = make_float2(re, im);
    }
}

// ---------------------------------------------------------------------------
// Fused beta-contraction + bf16 A-fragment pack (v2: no spills).
// Grid: (ma 32) x (zig 64) = 2048 blocks; thread = (zil 2, lq 4, ng 32).
// Each thread owns 4 l-values -> acc[4]+tl[4] stay in VGPRs (R4's acc[16]
// version spilled: VGPR_Count=40 < needed, 2% VALUBusy, 9k cyc/iter).
// Xf value is shared by the 4 lq-lanes at the same address (wave broadcast).
// ---------------------------------------------------------------------------
__global__ __launch_bounds__(256) void k_beta_A(const float2* __restrict__ Xf,
                                                const float* __restrict__ wf,
                                                u16* __restrict__ Ab) {
    int ma  = blockIdx.x >> 6;
    int zig = blockIdx.x & 63;
    int tid = threadIdx.x;
    int ng  = tid & 31;
    int lq  = (tid >> 5) & 3;
    int zil = tid >> 7;
    int zi  = zig * 2 + zil;
    int z = zi >> 5, i = zi & 31;
    int mh = (ma <= 15) ? ma : ma - 32;
    int nh = (ng <= 15) ? ng : ng - 32;
    int am = mh < 0 ? -mh : mh;
    int an = nh < 0 ? -nh : nh;
    int l0 = am > an ? am : an;    // 16 possible (ma==16 or ng==16) -> all skipped
    int lb = lq * 4;

    int tl[4];
#pragma unroll
    for (int j = 0; j < 4; j++) {
        int l = lb + j;
        tl[j] = LB[l] + (mh + l) * (2 * l + 1) + (nh + l);
    }
    float2 acc[4];
#pragma unroll
    for (int j = 0; j < 4; j++) acc[j] = make_float2(0.f, 0.f);

    const float2* xp = Xf + (size_t)zi * 32 * 1024 + (ma << 5) + ng;
#pragma unroll 4
    for (int b = 0; b < 32; b++) {
        float2 v = xp[(size_t)b * 1024];
        const float* wfb = wf + b * LTOT;
#pragma unroll
        for (int j = 0; j < 4; j++) {
            if (lb + j >= l0) {
                float w = wfb[tl[j]];
                acc[j].x += w * v.x;
                acc[j].y += w * v.y;
            }
        }
    }
    int s_i  = i >> 4;
    int kl   = 2 * (i & 15);
    int joff = kl & 7;
    int Lhi  = (kl >> 3) << 4;
#pragma unroll
    for (int j = 0; j < 4; j++) {
        int l = lb + j;
        if (l >= l0) {
            int mi = mh + l, ni = nh + l;
            int s   = 2 * ni + s_i;
            int row = 4 * mi + z;
            u32 pack = (u32)f2bf(acc[j].x) | ((u32)f2bf(acc[j].y) << 16);
            size_t off = (size_t)8192 * l * l + (size_t)s * 4096
                       + ((row >> 4) << 9) + ((Lhi + (row & 15)) << 3) + joff;
            *(u32*)(Ab + off) = pack;
        }
    }
}

// ---------------------------------------------------------------------------
// Build compact bf16 yh: yhb[t2][io] = pack(bf16(re), bf16(im)) of D*kernel.
// ---------------------------------------------------------------------------
__global__ __launch_bounds__(256) void k_prep_B(const float* __restrict__ Dre,
                                                const float* __restrict__ Dim,
                                                const float* __restrict__ ker,
                                                u32* __restrict__ yhb) {
    __shared__ float Ds[8][24];
    int t0  = blockIdx.x * 8;
    int tid = threadIdx.x;
    if (tid < 192) {
        int rr = tid / 24, jj = tid - rr * 24;
        Ds[rr][jj] = (jj < 12) ? Dre[(t0 + rr) * 12 + jj] : Dim[(t0 + rr) * 12 + jj - 12];
    }
    __syncthreads();
    for (int rep = 0; rep < 8; rep++) {
        int io = rep * 256 + tid;
        const float4* kp = (const float4*)(ker + io * 12);
        float4 ka = kp[0], kb = kp[1], kc = kp[2];
        float kv[12] = {ka.x, ka.y, ka.z, ka.w, kb.x, kb.y, kb.z, kb.w,
                        kc.x, kc.y, kc.z, kc.w};
#pragma unroll
        for (int rr = 0; rr < 8; rr++) {
            float sr = 0.f, si = 0.f;
#pragma unroll
            for (int j = 0; j < 12; j++) {
                sr += Ds[rr][j]      * kv[j];
                si += Ds[rr][12 + j] * kv[j];
            }
            yhb[(size_t)(t0 + rr) * 2048 + io] = (u32)f2bf(sr) | ((u32)f2bf(si) << 16);
        }
    }
}

// ---------------------------------------------------------------------------
// MFMA GEMM. 512 blocks = sum_l 2*(2l+1), big l first: block = (l, n, oh).
// Output transposed: zh_T[zo][t] (float pairs) for k_inv2's coalesced gather.
// ---------------------------------------------------------------------------
__global__ __launch_bounds__(256) void k_gemm(const u16* __restrict__ Ab,
                                              const u32* __restrict__ yhb,
                                              float* __restrict__ zhT) {
    __shared__ __align__(16) u16 As[4096];
    __shared__ __align__(16) u16 Bs[2048];

    int rem = blockIdx.x, l, nl = 1;
    for (l = 15; l >= 0; l--) {
        nl = 2 * l + 1;
        int c = nl * 2;
        if (rem < c) break;
        rem -= c;
    }
    int n  = rem >> 1;
    int oh = rem & 1;
    int base = LB[l];
    const u16* Ag = Ab + (size_t)8192 * l * l;
    int S = 2 * nl;

    int tid = threadIdx.x, lane = tid & 63, w = tid >> 6;

    int kh = (tid >> 4) & 3;
    int nu = ((tid >> 6) << 4) + (tid & 15);
    int oo = (oh << 5) + (nu >> 1);
    int cc = nu & 1;

    floatx4 acc[2][4];
#pragma unroll
    for (int a = 0; a < 2; a++)
#pragma unroll
        for (int b = 0; b < 4; b++) acc[a][b] = (floatx4)0.f;

    for (int s = 0; s < S; s++) {
        const uint4* ap = (const uint4*)(Ag + (size_t)s * 4096);
        uint4 a0 = ap[tid * 2], a1 = ap[tid * 2 + 1];
        int k = s >> 1, ih = s & 1;
        const u32* yr = yhb + (size_t)(base + k * nl + n) * 2048
                        + (((ih << 4) + (kh << 2)) << 6) + oo;
        u32 b0 = yr[0], b1 = yr[64], b2 = yr[128], b3 = yr[192];
        u32 p0, p1, p2, p3;
        if (cc == 0) {
            p0 = (b0 & 0xffffu) | ((b0 >> 16) << 16 ^ 0x80000000u);
            p1 = (b1 & 0xffffu) | ((b1 >> 16) << 16 ^ 0x80000000u);
            p2 = (b2 & 0xffffu) | ((b2 >> 16) << 16 ^ 0x80000000u);
            p3 = (b3 & 0xffffu) | ((b3 >> 16) << 16 ^ 0x80000000u);
        } else {
            p0 = (b0 >> 16) | (b0 << 16);
            p1 = (b1 >> 16) | (b1 << 16);
            p2 = (b2 >> 16) | (b2 << 16);
            p3 = (b3 >> 16) | (b3 << 16);
        }
        {
            uint4* aq = (uint4*)&As[tid << 4];
            aq[0] = a0; aq[1] = a1;
            *(uint4*)&Bs[tid << 3] = make_uint4(p0, p1, p2, p3);
        }
        __syncthreads();
        short8 af0 = *(const short8*)&As[((w << 1) + 0) * 512 + (lane << 3)];
        short8 af1 = *(const short8*)&As[((w << 1) + 1) * 512 + (lane << 3)];
#pragma unroll
        for (int nt = 0; nt < 4; nt++) {
            short8 bf = *(const short8*)&Bs[nt * 512 + (lane << 3)];
            acc[0][nt] = __builtin_amdgcn_mfma_f32_16x16x32_bf16(af0, bf, acc[0][nt], 0, 0, 0);
            acc[1][nt] = __builtin_amdgcn_mfma_f32_16x16x32_bf16(af1, bf, acc[1][nt], 0, 0, 0);
        }
        __syncthreads();
    }

    int q = lane >> 4, cn = lane & 15;
#pragma unroll
    for (int mt = 0; mt < 2; mt++) {
#pragma unroll
        for (int nt = 0; nt < 4; nt++) {
            int nu2 = (nt << 4) + cn;
            int o2  = (oh << 5) + (nu2 >> 1);
            int c2  = nu2 & 1;
#pragma unroll
            for (int r = 0; r < 4; r++) {
                int R = (w << 5) + (mt << 4) + (q << 2) + r;
                int m = R >> 2, z = R & 3;
                if (m < nl) {
                    int t  = base + m * nl + n;
                    int zo = (z << 6) + o2;
                    zhT[((size_t)zo * LTOT + t) * 2 + c2] = acc[mt][nt][r];
                }
            }
        }
    }
}

// ---------------------------------------------------------------------------
// Inverse: block = (zo, beta-pair). Gather P bins directly from zh_T, then
// in-place radix-2 IDFT2, stage output plane in LDS, coalesced write + bias.
// Grid: 4096 = (zo 256) x (bp 16); 256 threads; LDS ~17.2 KB (stride 33).
// ---------------------------------------------------------------------------
__global__ __launch_bounds__(256) void k_inv2(const float2* __restrict__ zhT,
                                              const float* __restrict__ wi,
                                              const float* __restrict__ bias,
                                              float* __restrict__ out) {
    __shared__ float2 P[2][32 * 33];   // row stride 33: 66 floats = 2 mod 32 banks
    __shared__ float Wc[32], Ws[32];
    int tid = threadIdx.x;
    int zo = blockIdx.x >> 4;
    int bp = blockIdx.x & 15;
    int b0 = bp * 2;
    if (tid < 32) {
        float sv, cv;
        sincosf(6.28318530717958647692f * (float)tid / 32.0f, &sv, &cv);
        Wc[tid] = cv; Ws[tid] = sv;
    }
    // ---- gather phase: 4 bins per thread
    {
        int ng = tid & 31, mq = tid >> 5;
        int nh = (ng <= 15) ? ng : ng - 32;
        int an = nh < 0 ? -nh : nh;
        const float2* zr = zhT + (size_t)zo * LTOT;
        const float*  w0p = wi + (size_t)b0 * LTOT;
        const float*  w1p = w0p + LTOT;
#pragma unroll
        for (int j = 0; j < 4; j++) {
            int ma = mq + 8 * j;
            int mh = (ma <= 15) ? ma : ma - 32;
            int am = mh < 0 ? -mh : mh;
            int l0 = am > an ? am : an;
            float2 a0 = make_float2(0.f, 0.f), a1 = make_float2(0.f, 0.f);
#pragma unroll
            for (int l = 0; l < 16; l++) {
                if (l >= l0) {
                    int t = LB[l] + (mh + l) * (2 * l + 1) + (nh + l);
                    float2 zv = zr[t];
                    float w0 = w0p[t];
                    float w1 = w1p[t];
                    a0.x += w0 * zv.x; a0.y += w0 * zv.y;
                    a1.x += w1 * zv.x; a1.y += w1 * zv.y;
                }
            }
            P[0][ma * 33 + ng] = a0;
            P[1][ma * 33 + ng] = a1;
        }
    }
    __syncthreads();
    // ---- pass 1 (ng -> g), e^{+i}, radix-2, in-place per row
    {
        int p = tid >> 7, rr = tid & 127;
        int ma = rr >> 2, q = rr & 3;
        float2* prow = &P[p][ma * 33];
        float2 row[32];
#pragma unroll
        for (int ngi = 0; ngi < 32; ngi++) row[ngi] = prow[ngi];
        float2 Tv[8];
#pragma unroll
        for (int jj = 0; jj < 4; jj++) {
            int k = q * 4 + jj;
            float2 E = make_float2(0.f, 0.f), O = make_float2(0.f, 0.f);
#pragma unroll
            for (int h = 0; h < 16; h++) {
                int idx = (2 * h * k) & 31;
                float c = Wc[idx], s = Ws[idx];
                float2 e = row[2 * h], o = row[2 * h + 1];
                E.x += e.x * c - e.y * s;  E.y += e.x * s + e.y * c;
                O.x += o.x * c - o.y * s;  O.y += o.x * s + o.y * c;
            }
            float c = Wc[k], s = Ws[k];
            float2 wO = make_float2(O.x * c - O.y * s, O.x * s + O.y * c);
            Tv[jj]     = make_float2(E.x + wO.x, E.y + wO.y);
            Tv[4 + jj] = make_float2(E.x - wO.x, E.y - wO.y);
        }
#pragma unroll
        for (int jj = 0; jj < 4; jj++) {
            prow[q * 4 + jj]      = Tv[jj];
            prow[q * 4 + jj + 16] = Tv[4 + jj];
        }
    }
    __syncthreads();
    // ---- pass 2 (ma -> a), real output, radix-2
    float vals[8];
    int p = tid >> 7, rr = tid & 127;
    int g = rr >> 2, q = rr & 3;
    {
        float2 col[32];
#pragma unroll
        for (int ma = 0; ma < 32; ma++) col[ma] = P[p][ma * 33 + g];
#pragma unroll
        for (int jj = 0; jj < 4; jj++) {
            int a = q * 4 + jj;
            float Ex = 0.f;
            float2 O = make_float2(0.f, 0.f);
#pragma unroll
            for (int h = 0; h < 16; h++) {
                int idx = (2 * h * a) & 31;
                float c = Wc[idx], s = Ws[idx];
                float2 e = col[2 * h], o = col[2 * h + 1];
                Ex  += e.x * c - e.y * s;
                O.x += o.x * c - o.y * s;
                O.y += o.x * s + o.y * c;
            }
            float wOx = O.x * Wc[a] - O.y * Ws[a];
            vals[jj]     = Ex + wOx;
            vals[4 + jj] = Ex - wOx;
        }
    }
    __syncthreads();
    float bv = bias[zo & 63];
    float* outS = (float*)&P[0][0];
#pragma unroll
    for (int jj = 0; jj < 4; jj++) {
        int a = q * 4 + jj;
        outS[p * 1024 + a * 32 + g]        = vals[jj]     * (1.f / 1024.f) + bv;
        outS[p * 1024 + (a + 16) * 32 + g] = vals[4 + jj] * (1.f / 1024.f) + bv;
    }
    __syncthreads();
    {
        int p2 = tid >> 7, r2 = tid & 127;
        const float4* sp = (const float4*)(outS + p2 * 1024);
        float4* dp = (float4*)(out + (size_t)zo * 32768 + (size_t)(b0 + p2) * 1024);
        dp[r2 * 2]     = sp[r2 * 2];
        dp[r2 * 2 + 1] = sp[r2 * 2 + 1];
    }
}

// ---------------------------------------------------------------------------
extern "C" void kernel_launch(void* const* d_in, const int* in_sizes, int n_in,
                              void* d_out, int out_size, void* d_ws, size_t ws_size,
                              hipStream_t stream) {
    const float* x    = (const float*)d_in[0];
    const float* ker  = (const float*)d_in[1];
    const float* bias = (const float*)d_in[2];
    const float* wf   = (const float*)d_in[3];
    const float* wi   = (const float*)d_in[4];
    const float* Dre  = (const float*)d_in[5];
    const float* Dim  = (const float*)d_in[6];
    float* out = (float*)d_out;

    // layout: buf0 = union(Xf 33.6MB, yhb 44.7MB) | Ab 4.2MB | zh_T 11.2MB
    char* ws = (char*)d_ws;
    float2* Xf  = (float2*)ws;
    u32*    yhb = (u32*)ws;
    u16*    Ab  = (u16*)(ws + 44695552);
    float*  zhT = (float*)(ws + 44695552 + 4194304);

    hipLaunchKernelGGL(k_fft_fwd, dim3(4096), dim3(256), 0, stream, x, Xf);
    hipLaunchKernelGGL(k_beta_A,  dim3(2048), dim3(256), 0, stream, Xf, wf, Ab);
    hipLaunchKernelGGL(k_prep_B,  dim3(682),  dim3(256), 0, stream, Dre, Dim, ker, yhb);
    hipLaunchKernelGGL(k_gemm,    dim3(512),  dim3(256), 0, stream, Ab, yhb, zhT);
    hipLaunchKernelGGL(k_inv2,    dim3(4096), dim3(256), 0, stream, (const float2*)zhT, wi, bias, out);
}

// Round 6
// 335.880 us; speedup vs baseline: 2.8768x; 1.0767x over previous
//
#include <hip/hip_runtime.h>
#include <math.h>

// ---------------------------------------------------------------------------
// SO3 convolution. Transforms fp32; block GEMM via bf16 MFMA (complex-as-real).
// Pipeline: k_fft_fwd (radix-2) -> k_beta_A -> k_prep_B -> k_gemm (MFMA)
//           -> k_inv2 (Hermitian gather + radix-2 IDFT, rows ma=0..15 only)
// zh stored transposed [zo][t] so k_inv2 gathers coalesced rows.
// Workspace: union(Xf, yhb) | Ab | zh_T   (~60 MB)
// ---------------------------------------------------------------------------

typedef unsigned short u16;
typedef unsigned int   u32;
typedef __attribute__((ext_vector_type(8))) short  short8;   // 8 bf16
typedef __attribute__((ext_vector_type(4))) float  floatx4;

constexpr int LTOT = 5456;
constexpr int ZO   = 256;    // z*64+o

constexpr int LB[17] = {0,1,10,35,84,165,286,455,680,969,
                        1330,1771,2300,2925,3654,4495,5456};

__device__ inline u16 f2bf(float f) {
    u32 u = __float_as_uint(f);
    u += 0x7fff + ((u >> 16) & 1);
    return (u16)(u >> 16);
}

// ---------------------------------------------------------------------------
// Forward FFT2 (e^{-i}) of one 32x32 plane per block, radix-2 both passes.
// x: [z][i][b][a][g].   Xf: [zi*32+b][ma][ng] complex.
// ---------------------------------------------------------------------------
__global__ __launch_bounds__(256) void k_fft_fwd(const float* __restrict__ x,
                                                 float2* __restrict__ Xf) {
    __shared__ float xs[1056];               // [a][g] stride 33
    __shared__ float Gre[1056], Gim[1056];   // [a][k] stride 33
    __shared__ float Wc[32], Ws[32];
    int tid = threadIdx.x;
    if (tid < 32) {
        float sv, cv;
        sincosf(6.28318530717958647692f * (float)tid / 32.0f, &sv, &cv);
        Wc[tid] = cv; Ws[tid] = sv;
    }
    const float* src = x + (size_t)blockIdx.x * 1024;
    for (int e = tid; e < 1024; e += 256) xs[(e >> 5) * 33 + (e & 31)] = src[e];
    __syncthreads();
    // pass 1 over g (real input), radix-2: 512 tasks (a, k in 0..15)
#pragma unroll
    for (int r = 0; r < 2; r++) {
        int e = tid + r * 256;
        int a = e >> 4, k = e & 15;
        const float* row = &xs[a * 33];
        float Er = 0.f, Ei = 0.f, Or = 0.f, Oi = 0.f;
#pragma unroll
        for (int h = 0; h < 16; h++) {
            int idx = (2 * h * k) & 31;
            float c = Wc[idx], s = Ws[idx];
            float xe = row[2 * h], xo = row[2 * h + 1];
            Er += xe * c;  Ei -= xe * s;
            Or += xo * c;  Oi -= xo * s;
        }
        // W^k = (Wc[k], -Ws[k]) forward twiddle
        float WOr = Or * Wc[k] + Oi * Ws[k];
        float WOi = Oi * Wc[k] - Or * Ws[k];
        Gre[a * 33 + k]      = Er + WOr;
        Gim[a * 33 + k]      = Ei + WOi;
        Gre[a * 33 + k + 16] = Er - WOr;
        Gim[a * 33 + k + 16] = Ei - WOi;
    }
    __syncthreads();
    // pass 2 over a (complex), radix-2: 512 tasks (ma in 0..15, ng)
    float2* dst = Xf + (size_t)blockIdx.x * 1024;
#pragma unroll
    for (int r = 0; r < 2; r++) {
        int e = tid + r * 256;
        int ng = e & 31, ma = e >> 5;
        float Er = 0.f, Ei = 0.f, Or = 0.f, Oi = 0.f;
#pragma unroll
        for (int h = 0; h < 16; h++) {
            int idx = (2 * h * ma) & 31;
            float c = Wc[idx], s = Ws[idx];
            float er = Gre[(2 * h) * 33 + ng],     ei = Gim[(2 * h) * 33 + ng];
            float orr = Gre[(2 * h + 1) * 33 + ng], oi = Gim[(2 * h + 1) * 33 + ng];
            Er += er * c + ei * s;   Ei += ei * c - er * s;
            Or += orr * c + oi * s;  Oi += oi * c - orr * s;
        }
        float WOr = Or * Wc[ma] + Oi * Ws[ma];
        float WOi = Oi * Wc[ma] - Or * Ws[ma];
        dst[ma * 32 + ng]        = make_float2(Er + WOr, Ei + WOi);
        dst[(ma + 16) * 32 + ng] = make_float2(Er - WOr, Ei - WOi);
    }
}

// ---------------------------------------------------------------------------
// Fused beta-contraction + bf16 A-fragment pack (4 l's per thread, no spills).
// Grid: (ma 32) x (zig 64) = 2048 blocks; thread = (zil 2, lq 4, ng 32).
// ---------------------------------------------------------------------------
__global__ __launch_bounds__(256) void k_beta_A(const float2* __restrict__ Xf,
                                                const float* __restrict__ wf,
                                                u16* __restrict__ Ab) {
    int ma  = blockIdx.x >> 6;
    int zig = blockIdx.x & 63;
    int tid = threadIdx.x;
    int ng  = tid & 31;
    int lq  = (tid >> 5) & 3;
    int zil = tid >> 7;
    int zi  = zig * 2 + zil;
    int z = zi >> 5, i = zi & 31;
    int mh = (ma <= 15) ? ma : ma - 32;
    int nh = (ng <= 15) ? ng : ng - 32;
    int am = mh < 0 ? -mh : mh;
    int an = nh < 0 ? -nh : nh;
    int l0 = am > an ? am : an;
    int lb = lq * 4;

    int tl[4];
#pragma unroll
    for (int j = 0; j < 4; j++) {
        int l = lb + j;
        tl[j] = LB[l] + (mh + l) * (2 * l + 1) + (nh + l);
    }
    float2 acc[4];
#pragma unroll
    for (int j = 0; j < 4; j++) acc[j] = make_float2(0.f, 0.f);

    const float2* xp = Xf + (size_t)zi * 32 * 1024 + (ma << 5) + ng;
#pragma unroll 4
    for (int b = 0; b < 32; b++) {
        float2 v = xp[(size_t)b * 1024];
        const float* wfb = wf + b * LTOT;
#pragma unroll
        for (int j = 0; j < 4; j++) {
            if (lb + j >= l0) {
                float w = wfb[tl[j]];
                acc[j].x += w * v.x;
                acc[j].y += w * v.y;
            }
        }
    }
    int s_i  = i >> 4;
    int kl   = 2 * (i & 15);
    int joff = kl & 7;
    int Lhi  = (kl >> 3) << 4;
#pragma unroll
    for (int j = 0; j < 4; j++) {
        int l = lb + j;
        if (l >= l0) {
            int mi = mh + l, ni = nh + l;
            int s   = 2 * ni + s_i;
            int row = 4 * mi + z;
            u32 pack = (u32)f2bf(acc[j].x) | ((u32)f2bf(acc[j].y) << 16);
            size_t off = (size_t)8192 * l * l + (size_t)s * 4096
                       + ((row >> 4) << 9) + ((Lhi + (row & 15)) << 3) + joff;
            *(u32*)(Ab + off) = pack;
        }
    }
}

// ---------------------------------------------------------------------------
// Build compact bf16 yh: yhb[t2][io] = pack(bf16(re), bf16(im)) of D*kernel.
// ---------------------------------------------------------------------------
__global__ __launch_bounds__(256) void k_prep_B(const float* __restrict__ Dre,
                                                const float* __restrict__ Dim,
                                                const float* __restrict__ ker,
                                                u32* __restrict__ yhb) {
    __shared__ float Ds[8][24];
    int t0  = blockIdx.x * 8;
    int tid = threadIdx.x;
    if (tid < 192) {
        int rr = tid / 24, jj = tid - rr * 24;
        Ds[rr][jj] = (jj < 12) ? Dre[(t0 + rr) * 12 + jj] : Dim[(t0 + rr) * 12 + jj - 12];
    }
    __syncthreads();
    for (int rep = 0; rep < 8; rep++) {
        int io = rep * 256 + tid;
        const float4* kp = (const float4*)(ker + io * 12);
        float4 ka = kp[0], kb = kp[1], kc = kp[2];
        float kv[12] = {ka.x, ka.y, ka.z, ka.w, kb.x, kb.y, kb.z, kb.w,
                        kc.x, kc.y, kc.z, kc.w};
#pragma unroll
        for (int rr = 0; rr < 8; rr++) {
            float sr = 0.f, si = 0.f;
#pragma unroll
            for (int j = 0; j < 12; j++) {
                sr += Ds[rr][j]      * kv[j];
                si += Ds[rr][12 + j] * kv[j];
            }
            yhb[(size_t)(t0 + rr) * 2048 + io] = (u32)f2bf(sr) | ((u32)f2bf(si) << 16);
        }
    }
}

// ---------------------------------------------------------------------------
// MFMA GEMM. 512 blocks = sum_l 2*(2l+1), big l first: block = (l, n, oh).
// Output transposed: zh_T[zo][t] (float pairs).
// ---------------------------------------------------------------------------
__global__ __launch_bounds__(256) void k_gemm(const u16* __restrict__ Ab,
                                              const u32* __restrict__ yhb,
                                              float* __restrict__ zhT) {
    __shared__ __align__(16) u16 As[4096];
    __shared__ __align__(16) u16 Bs[2048];

    int rem = blockIdx.x, l, nl = 1;
    for (l = 15; l >= 0; l--) {
        nl = 2 * l + 1;
        int c = nl * 2;
        if (rem < c) break;
        rem -= c;
    }
    int n  = rem >> 1;
    int oh = rem & 1;
    int base = LB[l];
    const u16* Ag = Ab + (size_t)8192 * l * l;
    int S = 2 * nl;

    int tid = threadIdx.x, lane = tid & 63, w = tid >> 6;

    int kh = (tid >> 4) & 3;
    int nu = ((tid >> 6) << 4) + (tid & 15);
    int oo = (oh << 5) + (nu >> 1);
    int cc = nu & 1;

    floatx4 acc[2][4];
#pragma unroll
    for (int a = 0; a < 2; a++)
#pragma unroll
        for (int b = 0; b < 4; b++) acc[a][b] = (floatx4)0.f;

    for (int s = 0; s < S; s++) {
        const uint4* ap = (const uint4*)(Ag + (size_t)s * 4096);
        uint4 a0 = ap[tid * 2], a1 = ap[tid * 2 + 1];
        int k = s >> 1, ih = s & 1;
        const u32* yr = yhb + (size_t)(base + k * nl + n) * 2048
                        + (((ih << 4) + (kh << 2)) << 6) + oo;
        u32 b0 = yr[0], b1 = yr[64], b2 = yr[128], b3 = yr[192];
        u32 p0, p1, p2, p3;
        if (cc == 0) {
            p0 = (b0 & 0xffffu) | ((b0 >> 16) << 16 ^ 0x80000000u);
            p1 = (b1 & 0xffffu) | ((b1 >> 16) << 16 ^ 0x80000000u);
            p2 = (b2 & 0xffffu) | ((b2 >> 16) << 16 ^ 0x80000000u);
            p3 = (b3 & 0xffffu) | ((b3 >> 16) << 16 ^ 0x80000000u);
        } else {
            p0 = (b0 >> 16) | (b0 << 16);
            p1 = (b1 >> 16) | (b1 << 16);
            p2 = (b2 >> 16) | (b2 << 16);
            p3 = (b3 >> 16) | (b3 << 16);
        }
        {
            uint4* aq = (uint4*)&As[tid << 4];
            aq[0] = a0; aq[1] = a1;
            *(uint4*)&Bs[tid << 3] = make_uint4(p0, p1, p2, p3);
        }
        __syncthreads();
        short8 af0 = *(const short8*)&As[((w << 1) + 0) * 512 + (lane << 3)];
        short8 af1 = *(const short8*)&As[((w << 1) + 1) * 512 + (lane << 3)];
#pragma unroll
        for (int nt = 0; nt < 4; nt++) {
            short8 bf = *(const short8*)&Bs[nt * 512 + (lane << 3)];
            acc[0][nt] = __builtin_amdgcn_mfma_f32_16x16x32_bf16(af0, bf, acc[0][nt], 0, 0, 0);
            acc[1][nt] = __builtin_amdgcn_mfma_f32_16x16x32_bf16(af1, bf, acc[1][nt], 0, 0, 0);
        }
        __syncthreads();
    }

    int q = lane >> 4, cn = lane & 15;
#pragma unroll
    for (int mt = 0; mt < 2; mt++) {
#pragma unroll
        for (int nt = 0; nt < 4; nt++) {
            int nu2 = (nt << 4) + cn;
            int o2  = (oh << 5) + (nu2 >> 1);
            int c2  = nu2 & 1;
#pragma unroll
            for (int r = 0; r < 4; r++) {
                int R = (w << 5) + (mt << 4) + (q << 2) + r;
                int m = R >> 2, z = R & 3;
                if (m < nl) {
                    int t  = base + m * nl + n;
                    int zo = (z << 6) + o2;
                    zhT[((size_t)zo * LTOT + t) * 2 + c2] = acc[mt][nt][r];
                }
            }
        }
    }
}

// ---------------------------------------------------------------------------
// Inverse, Hermitian-half version. Output is real => P[-ma,-ng]=conj(P[ma,ng])
// and row ma=16 is structurally empty. Gather only rows ma=0..15 (mh>=0 half
// of the t-space, 2856/5456 terms); pass 2 doubles the ma=1..15 contribution.
// Block = (zo, beta-pair): 2 planes x 16 rows x 32 ng.
// Grid: 4096 = (zo 256) x (bp 16); 256 threads; LDS ~8.9 KB.
// ---------------------------------------------------------------------------
__global__ __launch_bounds__(256) void k_inv2(const float2* __restrict__ zhT,
                                              const float* __restrict__ wi,
                                              const float* __restrict__ bias,
                                              float* __restrict__ out) {
    __shared__ float2 Pb[1088];        // P: plane p at p*528, rows ma 0..15 stride 33
    __shared__ float Wc[32], Ws[32];
    int tid = threadIdx.x;
    int zo = blockIdx.x >> 4;
    int bp = blockIdx.x & 15;
    int b0 = bp * 2;
    if (tid < 32) {
        float sv, cv;
        sincosf(6.28318530717958647692f * (float)tid / 32.0f, &sv, &cv);
        Wc[tid] = cv; Ws[tid] = sv;
    }
    // ---- gather: 4 (plane,ma) rows per thread, ma = mh in 0..15 only
    {
        int ng = tid & 31, rq = tid >> 5;      // rq 0..7
        int nh = (ng <= 15) ? ng : ng - 32;
        int an = nh < 0 ? -nh : nh;
        const float2* zr = zhT + (size_t)zo * LTOT;
#pragma unroll
        for (int j = 0; j < 4; j++) {
            int rowid = rq + 8 * j;            // 0..31
            int p  = rowid >> 4;
            int ma = rowid & 15;
            const float* wp = wi + (size_t)(b0 + p) * LTOT;
            int l0 = ma > an ? ma : an;
            float2 a0 = make_float2(0.f, 0.f);
#pragma unroll
            for (int l = 0; l < 16; l++) {
                if (l >= l0) {
                    int t = LB[l] + (ma + l) * (2 * l + 1) + (nh + l);
                    float w = wp[t];
                    float2 zv = zr[t];
                    a0.x += w * zv.x;
                    a0.y += w * zv.y;
                }
            }
            Pb[p * 528 + ma * 33 + ng] = a0;
        }
    }
    __syncthreads();
    // ---- pass 1 (ng -> g), e^{+i}, radix-2, in-place. 32 row-tasks x 8 thr.
    {
        int rowid = tid >> 3, q = tid & 7;
        float2* prow = &Pb[(rowid >> 4) * 528 + (rowid & 15) * 33];
        float2 row[32];
#pragma unroll
        for (int ngi = 0; ngi < 32; ngi++) row[ngi] = prow[ngi];
        float2 outv[4];
#pragma unroll
        for (int kk = 0; kk < 2; kk++) {
            int k = q + kk * 8;
            float2 E = make_float2(0.f, 0.f), O = make_float2(0.f, 0.f);
#pragma unroll
            for (int h = 0; h < 16; h++) {
                int idx = (2 * h * k) & 31;
                float c = Wc[idx], s = Ws[idx];
                float2 e = row[2 * h], o = row[2 * h + 1];
                E.x += e.x * c - e.y * s;  E.y += e.x * s + e.y * c;
                O.x += o.x * c - o.y * s;  O.y += o.x * s + o.y * c;
            }
            float c = Wc[k], s = Ws[k];
            float2 wO = make_float2(O.x * c - O.y * s, O.x * s + O.y * c);
            outv[kk * 2]     = make_float2(E.x + wO.x, E.y + wO.y);
            outv[kk * 2 + 1] = make_float2(E.x - wO.x, E.y - wO.y);
        }
        prow[q]          = outv[0];
        prow[q + 16]     = outv[1];
        prow[q + 8]      = outv[2];
        prow[q + 24]     = outv[3];
    }
    __syncthreads();
    // ---- pass 2 (ma -> a): out[a,g] = Re(T0) + 2*sum_{ma=1..15} Re(T e^{i th ma a})
    // radix-2 over ma parity: out[a] = Ea+Oa, out[a+16] = Ea-Oa  (a in 0..15)
    float vals[8];
    int p  = tid >> 7;
    int rr = tid & 127;
    int g  = rr & 31, qa = rr >> 5;
    {
        float2 col[16];
        const float2* pc = &Pb[p * 528];
#pragma unroll
        for (int ma = 0; ma < 16; ma++) col[ma] = pc[ma * 33 + g];
#pragma unroll
        for (int jj = 0; jj < 4; jj++) {
            int a = qa * 4 + jj;
            float Ea = col[0].x;                 // Re(T0), once
            float Oa = 0.f;
#pragma unroll
            for (int j = 1; j < 8; j++) {        // even ma = 2j
                int idx = ((2 * j) * a) & 31;
                Ea += 2.f * (col[2 * j].x * Wc[idx] - col[2 * j].y * Ws[idx]);
            }
#pragma unroll
            for (int j = 0; j < 8; j++) {        // odd ma = 2j+1
                int idx = ((2 * j + 1) * a) & 31;
                Oa += 2.f * (col[2 * j + 1].x * Wc[idx] - col[2 * j + 1].y * Ws[idx]);
            }
            vals[jj]     = Ea + Oa;
            vals[4 + jj] = Ea - Oa;
        }
    }
    __syncthreads();
    // ---- stage to LDS (stride-34 rows: 2-way max) and write out coalesced
    float bv = bias[zo & 63];
    float* outS = (float*)&Pb[0];                // 2*1088 floats = 8704 B
#pragma unroll
    for (int jj = 0; jj < 4; jj++) {
        int a = qa * 4 + jj;
        outS[p * 1088 + a * 34 + g]        = vals[jj]     * (1.f / 1024.f) + bv;
        outS[p * 1088 + (a + 16) * 34 + g] = vals[4 + jj] * (1.f / 1024.f) + bv;
    }
    __syncthreads();
    for (int e = tid; e < 2048; e += 256) {
        int p3 = e >> 10, rm = e & 1023;
        int a = rm >> 5, gg = rm & 31;
        out[(size_t)zo * 32768 + (size_t)(b0 + p3) * 1024 + rm] =
            outS[p3 * 1088 + a * 34 + gg];
    }
}

// ---------------------------------------------------------------------------
extern "C" void kernel_launch(void* const* d_in, const int* in_sizes, int n_in,
                              void* d_out, int out_size, void* d_ws, size_t ws_size,
                              hipStream_t stream) {
    const float* x    = (const float*)d_in[0];
    const float* ker  = (const float*)d_in[1];
    const float* bias = (const float*)d_in[2];
    const float* wf   = (const float*)d_in[3];
    const float* wi   = (const float*)d_in[4];
    const float* Dre  = (const float*)d_in[5];
    const float* Dim  = (const float*)d_in[6];
    float* out = (float*)d_out;

    // layout: buf0 = union(Xf 33.6MB, yhb 44.7MB) | Ab 4.2MB | zh_T 11.2MB
    char* ws = (char*)d_ws;
    float2* Xf  = (float2*)ws;
    u32*    yhb = (u32*)ws;
    u16*    Ab  = (u16*)(ws + 44695552);
    float*  zhT = (float*)(ws + 44695552 + 4194304);

    hipLaunchKernelGGL(k_fft_fwd, dim3(4096), dim3(256), 0, stream, x, Xf);
    hipLaunchKernelGGL(k_beta_A,  dim3(2048), dim3(256), 0, stream, Xf, wf, Ab);
    hipLaunchKernelGGL(k_prep_B,  dim3(682),  dim3(256), 0, stream, Dre, Dim, ker, yhb);
    hipLaunchKernelGGL(k_gemm,    dim3(512),  dim3(256), 0, stream, Ab, yhb, zhT);
    hipLaunchKernelGGL(k_inv2,    dim3(4096), dim3(256), 0, stream, (const float2*)zhT, wi, bias, out);
}

// Round 7
// 298.830 us; speedup vs baseline: 3.2335x; 1.1240x over previous
//
#include <hip/hip_runtime.h>
#include <math.h>

// ---------------------------------------------------------------------------
// SO3 convolution. Transforms fp32 compute; Xf stored bf16-packed; block GEMM
// via bf16 MFMA (complex-as-real).
// Pipeline: k_fft_fwd (radix-2, 512thr, bf16 out) -> k_beta_A -> k_prep_B
//           -> k_gemm (MFMA) -> k_inv2 (Hermitian gather + radix-2 IDFT)
// Workspace: union(Xfb 16.8MB, yhb 44.7MB) | Ab | zh_T   (~60 MB)
// ---------------------------------------------------------------------------

typedef unsigned short u16;
typedef unsigned int   u32;
typedef __attribute__((ext_vector_type(8))) short  short8;   // 8 bf16
typedef __attribute__((ext_vector_type(4))) float  floatx4;

constexpr int LTOT = 5456;
constexpr int ZO   = 256;    // z*64+o

constexpr int LB[17] = {0,1,10,35,84,165,286,455,680,969,
                        1330,1771,2300,2925,3654,4495,5456};

__device__ inline u16 f2bf(float f) {
    u32 u = __float_as_uint(f);
    u += 0x7fff + ((u >> 16) & 1);
    return (u16)(u >> 16);
}
__device__ inline u32 pack2bf(float re, float im) {
    return (u32)f2bf(re) | ((u32)f2bf(im) << 16);
}

// ---------------------------------------------------------------------------
// Forward FFT2 (e^{-i}) of one 32x32 plane per block, radix-2 both passes.
// 512 threads, ONE task per thread per pass (R6's 256-thr 2x-unroll version
// hit VGPR=136 -> 10% occupancy). Output bf16-packed (re|im) u32.
// x: [z][i][b][a][g].   Xfb: [zi*32+b][ma][ng] packed bf16 pairs.
// ---------------------------------------------------------------------------
__global__ __launch_bounds__(512) void k_fft_fwd(const float* __restrict__ x,
                                                 u32* __restrict__ Xfb) {
    __shared__ float xs[1056];               // [a][g] stride 33
    __shared__ float Gre[1056], Gim[1056];   // [a][k] stride 33
    __shared__ float Wc[32], Ws[32];
    int tid = threadIdx.x;
    if (tid < 32) {
        float sv, cv;
        sincosf(6.28318530717958647692f * (float)tid / 32.0f, &sv, &cv);
        Wc[tid] = cv; Ws[tid] = sv;
    }
    const float* src = x + (size_t)blockIdx.x * 1024;
    for (int e = tid; e < 1024; e += 512) xs[(e >> 5) * 33 + (e & 31)] = src[e];
    __syncthreads();
    // pass 1 over g (real input), radix-2: task = (a, k in 0..15)
    {
        int a = tid >> 4, k = tid & 15;
        const float* row = &xs[a * 33];
        float Er = 0.f, Ei = 0.f, Or = 0.f, Oi = 0.f;
#pragma unroll
        for (int h = 0; h < 16; h++) {
            int idx = (2 * h * k) & 31;
            float c = Wc[idx], s = Ws[idx];
            float xe = row[2 * h], xo = row[2 * h + 1];
            Er += xe * c;  Ei -= xe * s;
            Or += xo * c;  Oi -= xo * s;
        }
        float WOr = Or * Wc[k] + Oi * Ws[k];
        float WOi = Oi * Wc[k] - Or * Ws[k];
        Gre[a * 33 + k]      = Er + WOr;
        Gim[a * 33 + k]      = Ei + WOi;
        Gre[a * 33 + k + 16] = Er - WOr;
        Gim[a * 33 + k + 16] = Ei - WOi;
    }
    __syncthreads();
    // pass 2 over a (complex), radix-2: task = (ma in 0..15, ng)
    {
        u32* dst = Xfb + (size_t)blockIdx.x * 1024;
        int ng = tid & 31, ma = tid >> 5;
        float Er = 0.f, Ei = 0.f, Or = 0.f, Oi = 0.f;
#pragma unroll
        for (int h = 0; h < 16; h++) {
            int idx = (2 * h * ma) & 31;
            float c = Wc[idx], s = Ws[idx];
            float er = Gre[(2 * h) * 33 + ng],      ei = Gim[(2 * h) * 33 + ng];
            float orr = Gre[(2 * h + 1) * 33 + ng], oi = Gim[(2 * h + 1) * 33 + ng];
            Er += er * c + ei * s;   Ei += ei * c - er * s;
            Or += orr * c + oi * s;  Oi += oi * c - orr * s;
        }
        float WOr = Or * Wc[ma] + Oi * Ws[ma];
        float WOi = Oi * Wc[ma] - Or * Ws[ma];
        dst[ma * 32 + ng]        = pack2bf(Er + WOr, Ei + WOi);
        dst[(ma + 16) * 32 + ng] = pack2bf(Er - WOr, Ei - WOi);
    }
}

// ---------------------------------------------------------------------------
// Fused beta-contraction + bf16 A-fragment pack (4 l's per thread, no spills).
// Reads bf16-packed Xfb (unpack = 2 shifts).
// Grid: (ma 32) x (zig 64) = 2048 blocks; thread = (zil 2, lq 4, ng 32).
// ---------------------------------------------------------------------------
__global__ __launch_bounds__(256) void k_beta_A(const u32* __restrict__ Xfb,
                                                const float* __restrict__ wf,
                                                u16* __restrict__ Ab) {
    int ma  = blockIdx.x >> 6;
    int zig = blockIdx.x & 63;
    int tid = threadIdx.x;
    int ng  = tid & 31;
    int lq  = (tid >> 5) & 3;
    int zil = tid >> 7;
    int zi  = zig * 2 + zil;
    int z = zi >> 5, i = zi & 31;
    int mh = (ma <= 15) ? ma : ma - 32;
    int nh = (ng <= 15) ? ng : ng - 32;
    int am = mh < 0 ? -mh : mh;
    int an = nh < 0 ? -nh : nh;
    int l0 = am > an ? am : an;
    int lb = lq * 4;

    int tl[4];
#pragma unroll
    for (int j = 0; j < 4; j++) {
        int l = lb + j;
        tl[j] = LB[l] + (mh + l) * (2 * l + 1) + (nh + l);
    }
    float2 acc[4];
#pragma unroll
    for (int j = 0; j < 4; j++) acc[j] = make_float2(0.f, 0.f);

    const u32* xp = Xfb + (size_t)zi * 32 * 1024 + (ma << 5) + ng;
#pragma unroll 4
    for (int b = 0; b < 32; b++) {
        u32 pv = xp[(size_t)b * 1024];
        float vx = __uint_as_float(pv << 16);
        float vy = __uint_as_float(pv & 0xffff0000u);
        const float* wfb = wf + b * LTOT;
#pragma unroll
        for (int j = 0; j < 4; j++) {
            if (lb + j >= l0) {
                float w = wfb[tl[j]];
                acc[j].x += w * vx;
                acc[j].y += w * vy;
            }
        }
    }
    int s_i  = i >> 4;
    int kl   = 2 * (i & 15);
    int joff = kl & 7;
    int Lhi  = (kl >> 3) << 4;
#pragma unroll
    for (int j = 0; j < 4; j++) {
        int l = lb + j;
        if (l >= l0) {
            int mi = mh + l, ni = nh + l;
            int s   = 2 * ni + s_i;
            int row = 4 * mi + z;
            u32 pack = pack2bf(acc[j].x, acc[j].y);
            size_t off = (size_t)8192 * l * l + (size_t)s * 4096
                       + ((row >> 4) << 9) + ((Lhi + (row & 15)) << 3) + joff;
            *(u32*)(Ab + off) = pack;
        }
    }
}

// ---------------------------------------------------------------------------
// Build compact bf16 yh: yhb[t2][io] = pack(bf16(re), bf16(im)) of D*kernel.
// ---------------------------------------------------------------------------
__global__ __launch_bounds__(256) void k_prep_B(const float* __restrict__ Dre,
                                                const float* __restrict__ Dim,
                                                const float* __restrict__ ker,
                                                u32* __restrict__ yhb) {
    __shared__ float Ds[8][24];
    int t0  = blockIdx.x * 8;
    int tid = threadIdx.x;
    if (tid < 192) {
        int rr = tid / 24, jj = tid - rr * 24;
        Ds[rr][jj] = (jj < 12) ? Dre[(t0 + rr) * 12 + jj] : Dim[(t0 + rr) * 12 + jj - 12];
    }
    __syncthreads();
    for (int rep = 0; rep < 8; rep++) {
        int io = rep * 256 + tid;
        const float4* kp = (const float4*)(ker + io * 12);
        float4 ka = kp[0], kb = kp[1], kc = kp[2];
        float kv[12] = {ka.x, ka.y, ka.z, ka.w, kb.x, kb.y, kb.z, kb.w,
                        kc.x, kc.y, kc.z, kc.w};
#pragma unroll
        for (int rr = 0; rr < 8; rr++) {
            float sr = 0.f, si = 0.f;
#pragma unroll
            for (int j = 0; j < 12; j++) {
                sr += Ds[rr][j]      * kv[j];
                si += Ds[rr][12 + j] * kv[j];
            }
            yhb[(size_t)(t0 + rr) * 2048 + io] = pack2bf(sr, si);
        }
    }
}

// ---------------------------------------------------------------------------
// MFMA GEMM. 512 blocks = sum_l 2*(2l+1), big l first: block = (l, n, oh).
// Output transposed: zh_T[zo][t] (float pairs).
// ---------------------------------------------------------------------------
__global__ __launch_bounds__(256) void k_gemm(const u16* __restrict__ Ab,
                                              const u32* __restrict__ yhb,
                                              float* __restrict__ zhT) {
    __shared__ __align__(16) u16 As[4096];
    __shared__ __align__(16) u16 Bs[2048];

    int rem = blockIdx.x, l, nl = 1;
    for (l = 15; l >= 0; l--) {
        nl = 2 * l + 1;
        int c = nl * 2;
        if (rem < c) break;
        rem -= c;
    }
    int n  = rem >> 1;
    int oh = rem & 1;
    int base = LB[l];
    const u16* Ag = Ab + (size_t)8192 * l * l;
    int S = 2 * nl;

    int tid = threadIdx.x, lane = tid & 63, w = tid >> 6;

    int kh = (tid >> 4) & 3;
    int nu = ((tid >> 6) << 4) + (tid & 15);
    int oo = (oh << 5) + (nu >> 1);
    int cc = nu & 1;

    floatx4 acc[2][4];
#pragma unroll
    for (int a = 0; a < 2; a++)
#pragma unroll
        for (int b = 0; b < 4; b++) acc[a][b] = (floatx4)0.f;

    for (int s = 0; s < S; s++) {
        const uint4* ap = (const uint4*)(Ag + (size_t)s * 4096);
        uint4 a0 = ap[tid * 2], a1 = ap[tid * 2 + 1];
        int k = s >> 1, ih = s & 1;
        const u32* yr = yhb + (size_t)(base + k * nl + n) * 2048
                        + (((ih << 4) + (kh << 2)) << 6) + oo;
        u32 b0 = yr[0], b1 = yr[64], b2 = yr[128], b3 = yr[192];
        u32 p0, p1, p2, p3;
        if (cc == 0) {
            p0 = (b0 & 0xffffu) | ((b0 >> 16) << 16 ^ 0x80000000u);
            p1 = (b1 & 0xffffu) | ((b1 >> 16) << 16 ^ 0x80000000u);
            p2 = (b2 & 0xffffu) | ((b2 >> 16) << 16 ^ 0x80000000u);
            p3 = (b3 & 0xffffu) | ((b3 >> 16) << 16 ^ 0x80000000u);
        } else {
            p0 = (b0 >> 16) | (b0 << 16);
            p1 = (b1 >> 16) | (b1 << 16);
            p2 = (b2 >> 16) | (b2 << 16);
            p3 = (b3 >> 16) | (b3 << 16);
        }
        {
            uint4* aq = (uint4*)&As[tid << 4];
            aq[0] = a0; aq[1] = a1;
            *(uint4*)&Bs[tid << 3] = make_uint4(p0, p1, p2, p3);
        }
        __syncthreads();
        short8 af0 = *(const short8*)&As[((w << 1) + 0) * 512 + (lane << 3)];
        short8 af1 = *(const short8*)&As[((w << 1) + 1) * 512 + (lane << 3)];
#pragma unroll
        for (int nt = 0; nt < 4; nt++) {
            short8 bf = *(const short8*)&Bs[nt * 512 + (lane << 3)];
            acc[0][nt] = __builtin_amdgcn_mfma_f32_16x16x32_bf16(af0, bf, acc[0][nt], 0, 0, 0);
            acc[1][nt] = __builtin_amdgcn_mfma_f32_16x16x32_bf16(af1, bf, acc[1][nt], 0, 0, 0);
        }
        __syncthreads();
    }

    int q = lane >> 4, cn = lane & 15;
#pragma unroll
    for (int mt = 0; mt < 2; mt++) {
#pragma unroll
        for (int nt = 0; nt < 4; nt++) {
            int nu2 = (nt << 4) + cn;
            int o2  = (oh << 5) + (nu2 >> 1);
            int c2  = nu2 & 1;
#pragma unroll
            for (int r = 0; r < 4; r++) {
                int R = (w << 5) + (mt << 4) + (q << 2) + r;
                int m = R >> 2, z = R & 3;
                if (m < nl) {
                    int t  = base + m * nl + n;
                    int zo = (z << 6) + o2;
                    zhT[((size_t)zo * LTOT + t) * 2 + c2] = acc[mt][nt][r];
                }
            }
        }
    }
}

// ---------------------------------------------------------------------------
// Inverse, Hermitian-half (rows ma=0..15; conjugate half implied).
// Grid: 4096 = (zo 256) x (bp 16); 256 threads; LDS ~8.9 KB.
// ---------------------------------------------------------------------------
__global__ __launch_bounds__(256) void k_inv2(const float2* __restrict__ zhT,
                                              const float* __restrict__ wi,
                                              const float* __restrict__ bias,
                                              float* __restrict__ out) {
    __shared__ float2 Pb[1088];        // plane p at p*528, rows ma 0..15 stride 33
    __shared__ float Wc[32], Ws[32];
    int tid = threadIdx.x;
    int zo = blockIdx.x >> 4;
    int bp = blockIdx.x & 15;
    int b0 = bp * 2;
    if (tid < 32) {
        float sv, cv;
        sincosf(6.28318530717958647692f * (float)tid / 32.0f, &sv, &cv);
        Wc[tid] = cv; Ws[tid] = sv;
    }
    // ---- gather: 4 (plane,ma) rows per thread, ma = mh in 0..15 only
    {
        int ng = tid & 31, rq = tid >> 5;
        int nh = (ng <= 15) ? ng : ng - 32;
        int an = nh < 0 ? -nh : nh;
        const float2* zr = zhT + (size_t)zo * LTOT;
#pragma unroll
        for (int j = 0; j < 4; j++) {
            int rowid = rq + 8 * j;
            int p  = rowid >> 4;
            int ma = rowid & 15;
            const float* wp = wi + (size_t)(b0 + p) * LTOT;
            int l0 = ma > an ? ma : an;
            float2 a0 = make_float2(0.f, 0.f);
#pragma unroll
            for (int l = 0; l < 16; l++) {
                if (l >= l0) {
                    int t = LB[l] + (ma + l) * (2 * l + 1) + (nh + l);
                    float w = wp[t];
                    float2 zv = zr[t];
                    a0.x += w * zv.x;
                    a0.y += w * zv.y;
                }
            }
            Pb[p * 528 + ma * 33 + ng] = a0;
        }
    }
    __syncthreads();
    // ---- pass 1 (ng -> g), e^{+i}, radix-2, in-place. 32 row-tasks x 8 thr.
    {
        int rowid = tid >> 3, q = tid & 7;
        float2* prow = &Pb[(rowid >> 4) * 528 + (rowid & 15) * 33];
        float2 row[32];
#pragma unroll
        for (int ngi = 0; ngi < 32; ngi++) row[ngi] = prow[ngi];
        float2 outv[4];
#pragma unroll
        for (int kk = 0; kk < 2; kk++) {
            int k = q + kk * 8;
            float2 E = make_float2(0.f, 0.f), O = make_float2(0.f, 0.f);
#pragma unroll
            for (int h = 0; h < 16; h++) {
                int idx = (2 * h * k) & 31;
                float c = Wc[idx], s = Ws[idx];
                float2 e = row[2 * h], o = row[2 * h + 1];
                E.x += e.x * c - e.y * s;  E.y += e.x * s + e.y * c;
                O.x += o.x * c - o.y * s;  O.y += o.x * s + o.y * c;
            }
            float c = Wc[k], s = Ws[k];
            float2 wO = make_float2(O.x * c - O.y * s, O.x * s + O.y * c);
            outv[kk * 2]     = make_float2(E.x + wO.x, E.y + wO.y);
            outv[kk * 2 + 1] = make_float2(E.x - wO.x, E.y - wO.y);
        }
        prow[q]          = outv[0];
        prow[q + 16]     = outv[1];
        prow[q + 8]      = outv[2];
        prow[q + 24]     = outv[3];
    }
    __syncthreads();
    // ---- pass 2 (ma -> a): out = Re(T0) + 2*sum_{ma=1..15} Re(T e^{i th ma a})
    float vals[8];
    int p  = tid >> 7;
    int rr = tid & 127;
    int g  = rr & 31, qa = rr >> 5;
    {
        float2 col[16];
        const float2* pc = &Pb[p * 528];
#pragma unroll
        for (int ma = 0; ma < 16; ma++) col[ma] = pc[ma * 33 + g];
#pragma unroll
        for (int jj = 0; jj < 4; jj++) {
            int a = qa * 4 + jj;
            float Ea = col[0].x;
            float Oa = 0.f;
#pragma unroll
            for (int j = 1; j < 8; j++) {
                int idx = ((2 * j) * a) & 31;
                Ea += 2.f * (col[2 * j].x * Wc[idx] - col[2 * j].y * Ws[idx]);
            }
#pragma unroll
            for (int j = 0; j < 8; j++) {
                int idx = ((2 * j + 1) * a) & 31;
                Oa += 2.f * (col[2 * j + 1].x * Wc[idx] - col[2 * j + 1].y * Ws[idx]);
            }
            vals[jj]     = Ea + Oa;
            vals[4 + jj] = Ea - Oa;
        }
    }
    __syncthreads();
    float bv = bias[zo & 63];
    float* outS = (float*)&Pb[0];
#pragma unroll
    for (int jj = 0; jj < 4; jj++) {
        int a = qa * 4 + jj;
        outS[p * 1088 + a * 34 + g]        = vals[jj]     * (1.f / 1024.f) + bv;
        outS[p * 1088 + (a + 16) * 34 + g] = vals[4 + jj] * (1.f / 1024.f) + bv;
    }
    __syncthreads();
    for (int e = tid; e < 2048; e += 256) {
        int p3 = e >> 10, rm = e & 1023;
        int a = rm >> 5, gg = rm & 31;
        out[(size_t)zo * 32768 + (size_t)(b0 + p3) * 1024 + rm] =
            outS[p3 * 1088 + a * 34 + gg];
    }
}

// ---------------------------------------------------------------------------
extern "C" void kernel_launch(void* const* d_in, const int* in_sizes, int n_in,
                              void* d_out, int out_size, void* d_ws, size_t ws_size,
                              hipStream_t stream) {
    const float* x    = (const float*)d_in[0];
    const float* ker  = (const float*)d_in[1];
    const float* bias = (const float*)d_in[2];
    const float* wf   = (const float*)d_in[3];
    const float* wi   = (const float*)d_in[4];
    const float* Dre  = (const float*)d_in[5];
    const float* Dim  = (const float*)d_in[6];
    float* out = (float*)d_out;

    // layout: buf0 = union(Xfb 16.8MB, yhb 44.7MB) | Ab 4.2MB | zh_T 11.2MB
    char* ws = (char*)d_ws;
    u32*    Xfb = (u32*)ws;
    u32*    yhb = (u32*)ws;   // overlaps Xfb (dead after k_beta_A; stream-ordered)
    u16*    Ab  = (u16*)(ws + 44695552);
    float*  zhT = (float*)(ws + 44695552 + 4194304);

    hipLaunchKernelGGL(k_fft_fwd, dim3(4096), dim3(512), 0, stream, x, Xfb);
    hipLaunchKernelGGL(k_beta_A,  dim3(2048), dim3(256), 0, stream, Xfb, wf, Ab);
    hipLaunchKernelGGL(k_prep_B,  dim3(682),  dim3(256), 0, stream, Dre, Dim, ker, yhb);
    hipLaunchKernelGGL(k_gemm,    dim3(512),  dim3(256), 0, stream, Ab, yhb, zhT);
    hipLaunchKernelGGL(k_inv2,    dim3(4096), dim3(256), 0, stream, (const float2*)zhT, wi, bias, out);
}